// Round 6
// baseline (3154.953 us; speedup 1.0000x reference)
//
#include <hip/hip_runtime.h>
#include <hip/hip_cooperative_groups.h>

namespace cg = cooperative_groups;

#define DD   128
#define NL   8000
#define NC   16000
#define TSTEPS 8
#define NBF  2     // steps 0..1 bf16 6-term; steps 2..7 fp16 4-term
#define ROWW 96    // max clauses per literal (mean 40, std 6.3)
#define COLW 64    // max literals per clause (mean 20, std 4.4)
#define GRID 256   // cooperative grid: 1 block/CU, guaranteed co-resident

// clause kernels: 32-row tiles, K=256 -> 32 octs, stride 33 short8 (pad)
#define OS   33
#define SPLITS8 (32 * OS)        // oct-slots per plane = 1056
#define SPLIT   (SPLITS8 * 8)    // shorts per plane = 8448
// literal bf16: 16-row tiles, K=384 -> 48 octs, stride 17 short8
#define LSTR 17
#define LSPL (48 * LSTR * 8)     // shorts per plane = 6528
// literal fp16: 32-row tiles, K=384 -> 48 octs, stride 33 short8
#define L2S  33
#define L2SPL (48 * L2S * 8)     // shorts per plane = 12672

typedef __attribute__((ext_vector_type(8))) short  short8;
typedef __attribute__((ext_vector_type(8))) _Float16 half8;
typedef __attribute__((ext_vector_type(4))) float  f32x4;

__device__ __forceinline__ float frcp(float x) { return __builtin_amdgcn_rcpf(x); }
__device__ __forceinline__ float sigm(float x) { return frcp(1.f + __expf(-x)); }
__device__ __forceinline__ float tanh_(float x) {
  float e = __expf(2.f * x);
  return 1.f - 2.f * frcp(e + 1.f);
}
__device__ __forceinline__ void add4(float4& a, const float4 b) {
  a.x += b.x; a.y += b.y; a.z += b.z; a.w += b.w;
}
__device__ __forceinline__ unsigned short bfround(float v) {  // RNE fp32 -> bf16
  unsigned u = __float_as_uint(v);
  return (unsigned short)((u + 0x7FFF + ((u >> 16) & 1)) >> 16);
}
__device__ __forceinline__ float bf2f(unsigned short b) {
  return __uint_as_float(((unsigned)b) << 16);
}
__device__ __forceinline__ void splitf16(float v, unsigned short& h, unsigned short& l) {
  _Float16 hh = (_Float16)v;           // RNE
  float r = v - (float)hh;             // exact
  _Float16 ll = (_Float16)r;
  h = __builtin_bit_cast(unsigned short, hh);
  l = __builtin_bit_cast(unsigned short, ll);
}
__device__ __forceinline__ int4 packi4(const unsigned short* p) {
  return make_int4(p[0] | ((int)p[1] << 16), p[2] | ((int)p[3] << 16),
                   p[4] | ((int)p[5] << 16), p[6] | ((int)p[7] << 16));
}

// bf16 triple-split 8 floats -> 3 octets, clause layout (stride OS, plane SPLIT)
__device__ __forceinline__ void store_oct3(unsigned short* A, int oct, int m,
                                           float4 a, float4 b) {
  float f[8] = {a.x, a.y, a.z, a.w, b.x, b.y, b.z, b.w};
  unsigned short h[8], md[8], lo[8];
  #pragma unroll
  for (int j = 0; j < 8; ++j) {
    h[j] = bfround(f[j]);
    float r1 = f[j] - bf2f(h[j]);       // exact (Sterbenz)
    md[j] = bfround(r1);
    float r2 = r1 - bf2f(md[j]);        // exact
    lo[j] = bfround(r2);
  }
  int base = (oct * OS + m) * 8;
  *(int4*)(A + base)             = packi4(h);
  *(int4*)(A + SPLIT + base)     = packi4(md);
  *(int4*)(A + 2 * SPLIT + base) = packi4(lo);
}

// fp16 2-split 8 floats -> 2 octets, generic layout (strideS8 slots, plane in shorts)
__device__ __forceinline__ void store_oct2g(unsigned short* A, int strideS8, int plane,
                                            int oct, int m, float4 a, float4 b) {
  float f[8] = {a.x, a.y, a.z, a.w, b.x, b.y, b.z, b.w};
  unsigned short h[8], lo[8];
  #pragma unroll
  for (int j = 0; j < 8; ++j) splitf16(f[j], h[j], lo[j]);
  int base = (oct * strideS8 + m) * 8;
  *(int4*)(A + base)         = packi4(h);
  *(int4*)(A + plane + base) = packi4(lo);
}

// bf16 triple-split 4 floats -> half-octet, 16-row literal layout
__device__ __forceinline__ void store_half3L(unsigned short* A, int oct, int half, int m,
                                             float4 a) {
  float f[4] = {a.x, a.y, a.z, a.w};
  unsigned short h[4], md[4], lo[4];
  #pragma unroll
  for (int j = 0; j < 4; ++j) {
    h[j] = bfround(f[j]);
    float r1 = f[j] - bf2f(h[j]);
    md[j] = bfround(r1);
    float r2 = r1 - bf2f(md[j]);
    lo[j] = bfround(r2);
  }
  int base = (oct * LSTR + m) * 8 + half * 4;
  *(int2*)(A + base)            = make_int2(h[0]  | ((int)h[1]  << 16), h[2]  | ((int)h[3]  << 16));
  *(int2*)(A + LSPL + base)     = make_int2(md[0] | ((int)md[1] << 16), md[2] | ((int)md[3] << 16));
  *(int2*)(A + 2 * LSPL + base) = make_int2(lo[0] | ((int)lo[1] << 16), lo[2] | ((int)lo[3] << 16));
}

__device__ __forceinline__ void split_store_bf3(float w, int idx, unsigned short* hi,
                                                unsigned short* md, unsigned short* lo) {
  unsigned short h = bfround(w);
  float r1 = w - bf2f(h);
  unsigned short m = bfround(r1);
  float r2 = r1 - bf2f(m);
  hi[idx] = h; md[idx] = m; lo[idx] = bfround(r2);
}

// 6-term bf16 triple-split product (error ~2^-27)
#define MFMA6(ACC, AH, AM, AL, BH, BM, BL)                                   \
  ACC = __builtin_amdgcn_mfma_f32_16x16x32_bf16(AH, BH, ACC, 0, 0, 0);       \
  ACC = __builtin_amdgcn_mfma_f32_16x16x32_bf16(AH, BM, ACC, 0, 0, 0);       \
  ACC = __builtin_amdgcn_mfma_f32_16x16x32_bf16(AM, BH, ACC, 0, 0, 0);       \
  ACC = __builtin_amdgcn_mfma_f32_16x16x32_bf16(AH, BL, ACC, 0, 0, 0);       \
  ACC = __builtin_amdgcn_mfma_f32_16x16x32_bf16(AL, BH, ACC, 0, 0, 0);       \
  ACC = __builtin_amdgcn_mfma_f32_16x16x32_bf16(AM, BM, ACC, 0, 0, 0);

// 4-term fp16 2-split product (error ~2^-22 rep residual)
#define MFMA4(ACC, AH, AL, BH, BL)                                           \
  ACC = __builtin_amdgcn_mfma_f32_16x16x32_f16(AH, BH, ACC, 0, 0, 0);        \
  ACC = __builtin_amdgcn_mfma_f32_16x16x32_f16(AH, BL, ACC, 0, 0, 0);        \
  ACC = __builtin_amdgcn_mfma_f32_16x16x32_f16(AL, BH, ACC, 0, 0, 0);        \
  ACC = __builtin_amdgcn_mfma_f32_16x16x32_f16(AL, BL, ACC, 0, 0, 0);

// ---------------- shared LDS union (max member 62,976 B < 64 KB) ----------------
union alignas(16) SmemU {
  struct { unsigned short A[3 * SPLIT];  int IDX[32 * COLW]; } cb3;  // 50,688+8,192
  struct { unsigned short A[3 * LSPL];   int IDX[16 * ROWW]; } lb3;  // 39,168+6,144
  struct { unsigned short A[2 * SPLIT];  int IDX[32 * COLW]; } cf2;  // 33,792+8,192
  struct { unsigned short A[2 * L2SPL];  int IDX[32 * ROWW]; } lf2;  // 50,688+12,288
};

// ---------------- shared epilogues ----------------
__device__ __forceinline__ void clause_epilogue(
    const f32x4 acc[2][4], const float* bsum, const float* bvec, const int* ccnt,
    float* hC, float* Cs, int rowBase, int quad, int cw) {
  float bs_[4], bv_[4];
  #pragma unroll
  for (int g = 0; g < 4; ++g) { bs_[g] = bsum[g * 128 + cw]; bv_[g] = bvec[g * 128 + cw]; }
  #pragma unroll
  for (int mt = 0; mt < 2; ++mt) {
    #pragma unroll
    for (int reg = 0; reg < 4; ++reg) {
      int row = rowBase + mt * 16 + quad * 4 + reg;
      float deg = (float)ccnt[row];
      float co = hC[(size_t)row * DD + cw];
      float iv = acc[mt][0][reg] + bs_[0] + deg * bv_[0];
      float fv = acc[mt][1][reg] + bs_[1] + deg * bv_[1];
      float gv = acc[mt][2][reg] + bs_[2] + deg * bv_[2];
      float ov = acc[mt][3][reg] + bs_[3] + deg * bv_[3];
      float cn = sigm(fv) * co + sigm(iv) * tanh_(gv);
      hC[(size_t)row * DD + cw] = cn;
      Cs[(size_t)row * DD + cw] = sigm(ov) * tanh_(cn);
    }
  }
}

__device__ __forceinline__ void literal_epilogue2(
    const f32x4 acc[2][4], const float* bsum, const float* bvec, const int* rcnt,
    float* hL, float* Lbuf, int rowBase, int quad, int cw) {
  float bs_[4], bv_[4];
  #pragma unroll
  for (int g = 0; g < 4; ++g) { bs_[g] = bsum[g * 128 + cw]; bv_[g] = bvec[g * 128 + cw]; }
  #pragma unroll
  for (int mt = 0; mt < 2; ++mt) {
    #pragma unroll
    for (int reg = 0; reg < 4; ++reg) {
      int row = rowBase + mt * 16 + quad * 4 + reg;
      float deg = (float)rcnt[row];
      float co = hL[(size_t)row * DD + cw];
      float iv = acc[mt][0][reg] + bs_[0] + deg * bv_[0];
      float fv = acc[mt][1][reg] + bs_[1] + deg * bv_[1];
      float gv = acc[mt][2][reg] + bs_[2] + deg * bv_[2];
      float ov = acc[mt][3][reg] + bs_[3] + deg * bv_[3];
      float cn = sigm(fv) * co + sigm(iv) * tanh_(gv);
      hL[(size_t)row * DD + cw] = cn;
      Lbuf[(size_t)row * DD + cw] = sigm(ov) * tanh_(cn);
    }
  }
}

// ---------------- per-tile step bodies (verbatim R2 structure) ----------------

template <int NOCT, bool STAGE_H>
__device__ __forceinline__ void clause_bf3_tile(
    SmemU& sm, int tile,
    const float* __restrict__ Lbuf, const int* __restrict__ csc, const int* __restrict__ ccnt,
    const unsigned short* __restrict__ pkhi, const unsigned short* __restrict__ pkmd,
    const unsigned short* __restrict__ pklo,
    const float* __restrict__ bsum, const float* __restrict__ bvec,
    float* __restrict__ hC, float* __restrict__ Cs) {
  unsigned short* A = sm.cb3.A;
  int* IDX = sm.cb3.IDX;
  const int t = threadIdx.x;
  const int rowBase = tile * 32;

  ((int4*)IDX)[t] = ((const int4*)(csc + rowBase * COLW))[t];
  __syncthreads();

  { // gather + stage: 16 threads/row, 8 floats each; K = [msgs | hC?]
    const int r = t >> 4, sub = t & 15;
    const int c = rowBase + r;
    int cnt = ccnt[c]; if (cnt > COLW) cnt = COLW;
    const int* lst = IDX + r * COLW;
    float4 a0 = make_float4(0, 0, 0, 0), a1 = a0;
    int j = 0;
    for (; j + 8 <= cnt; j += 8) {
      float4 p0[8], p1[8];
      #pragma unroll
      for (int u = 0; u < 8; ++u) {
        const float4* s4 = (const float4*)(Lbuf + (size_t)lst[j + u] * DD) + sub * 2;
        p0[u] = s4[0]; p1[u] = s4[1];
      }
      #pragma unroll
      for (int u = 0; u < 8; ++u) { add4(a0, p0[u]); add4(a1, p1[u]); }
    }
    for (; j < cnt; ++j) {
      const float4* s4 = (const float4*)(Lbuf + (size_t)lst[j] * DD) + sub * 2;
      add4(a0, s4[0]); add4(a1, s4[1]);
    }
    store_oct3(A, sub, r, a0, a1);
    if constexpr (STAGE_H) {
      const float4* h4 = (const float4*)(hC + (size_t)c * DD) + sub * 2;
      store_oct3(A, 16 + sub, r, h4[0], h4[1]);
    }
  }
  __syncthreads();

  const int w = t >> 6, l = t & 63;
  const int quad = l >> 4, lane16 = l & 15;
  const int cw = w * 16 + lane16;
  f32x4 acc[2][4];
  #pragma unroll
  for (int mt = 0; mt < 2; ++mt)
    #pragma unroll
    for (int g = 0; g < 4; ++g) acc[mt][g] = (f32x4){0.f, 0.f, 0.f, 0.f};

  const short8* As = (const short8*)A;
  const short8* Bh = (const short8*)pkhi;
  const short8* Bm = (const short8*)pkmd;
  const short8* Bl = (const short8*)pklo;

  __builtin_amdgcn_s_setprio(1);   // T5 (R2: +1.2%)
  #pragma unroll
  for (int s = 0; s < NOCT / 4; ++s) {
    int ao = (s * 4 + quad) * OS + lane16;
    short8 a0h = As[ao],                a1h = As[ao + 16];
    short8 a0m = As[SPLITS8 + ao],      a1m = As[SPLITS8 + ao + 16];
    short8 a0l = As[2 * SPLITS8 + ao],  a1l = As[2 * SPLITS8 + ao + 16];
    int bo = (s * 4 + quad) * 512 + cw;
    #pragma unroll
    for (int g = 0; g < 4; ++g) {
      short8 bh = Bh[bo + g * 128];
      short8 bm = Bm[bo + g * 128];
      short8 bl = Bl[bo + g * 128];
      MFMA6(acc[0][g], a0h, a0m, a0l, bh, bm, bl);
      MFMA6(acc[1][g], a1h, a1m, a1l, bh, bm, bl);
    }
  }
  __builtin_amdgcn_s_setprio(0);
  clause_epilogue(acc, bsum, bvec, ccnt, hC, Cs, rowBase, quad, cw);
}

template <int NOCT, bool STAGE_H>
__device__ __forceinline__ void literal_bf3_tile(
    SmemU& sm, int tile,
    const float* __restrict__ Cs, const int* __restrict__ csr, const int* __restrict__ rcnt,
    const unsigned short* __restrict__ pkhi, const unsigned short* __restrict__ pkmd,
    const unsigned short* __restrict__ pklo,
    const float* __restrict__ bsum, const float* __restrict__ bvec,
    float* __restrict__ hL, float* __restrict__ Lbuf) {
  unsigned short* A = sm.lb3.A;
  int* IDX = sm.lb3.IDX;
  const int t = threadIdx.x;
  const int rowBase = tile * 16;

  if (t < 384) ((int4*)IDX)[t] = ((const int4*)(csr + rowBase * ROWW))[t];
  __syncthreads();

  { // gather + stage: 32 threads/row, 4 floats each; K = [msgs | L | hL?]
    const int r = t >> 5, cg2 = t & 31;
    const int lr = rowBase + r;
    int cnt = rcnt[lr]; if (cnt > ROWW) cnt = ROWW;
    const int* lst = IDX + r * ROWW;
    float4 a0 = make_float4(0, 0, 0, 0);
    int j = 0;
    for (; j + 8 <= cnt; j += 8) {
      float4 p[8];
      #pragma unroll
      for (int u = 0; u < 8; ++u)
        p[u] = ((const float4*)(Cs + (size_t)lst[j + u] * DD))[cg2];
      #pragma unroll
      for (int u = 0; u < 8; ++u) add4(a0, p[u]);
    }
    for (; j < cnt; ++j)
      add4(a0, ((const float4*)(Cs + (size_t)lst[j] * DD))[cg2]);
    store_half3L(A, cg2 >> 1, cg2 & 1, r, a0);
    store_half3L(A, 16 + (cg2 >> 1), cg2 & 1, r,
                 ((const float4*)(Lbuf + (size_t)lr * DD))[cg2]);
    if constexpr (STAGE_H)
      store_half3L(A, 32 + (cg2 >> 1), cg2 & 1, r,
                   ((const float4*)(hL + (size_t)lr * DD))[cg2]);
  }
  __syncthreads();

  const int w = t >> 6, l = t & 63;
  const int quad = l >> 4, lane16 = l & 15;
  const int cw = w * 16 + lane16;
  f32x4 acc[4];
  #pragma unroll
  for (int g = 0; g < 4; ++g) acc[g] = (f32x4){0.f, 0.f, 0.f, 0.f};

  const short8* As = (const short8*)A;
  const short8* Bh = (const short8*)pkhi;
  const short8* Bm = (const short8*)pkmd;
  const short8* Bl = (const short8*)pklo;

  __builtin_amdgcn_s_setprio(1);   // T5
  #pragma unroll
  for (int s = 0; s < NOCT / 4; ++s) {
    int ao = (s * 4 + quad) * LSTR + lane16;
    short8 ah = As[ao];
    short8 am = As[LSPL / 8 + ao];
    short8 al = As[2 * (LSPL / 8) + ao];
    int bo = (s * 4 + quad) * 512 + cw;
    #pragma unroll
    for (int g = 0; g < 4; ++g) {
      short8 bh = Bh[bo + g * 128];
      short8 bm = Bm[bo + g * 128];
      short8 bl = Bl[bo + g * 128];
      MFMA6(acc[g], ah, am, al, bh, bm, bl);
    }
  }
  __builtin_amdgcn_s_setprio(0);

  float bs_[4], bv_[4];
  #pragma unroll
  for (int g = 0; g < 4; ++g) { bs_[g] = bsum[g * 128 + cw]; bv_[g] = bvec[g * 128 + cw]; }
  #pragma unroll
  for (int reg = 0; reg < 4; ++reg) {
    int row = rowBase + quad * 4 + reg;
    float deg = (float)rcnt[row];
    float co = hL[(size_t)row * DD + cw];
    float iv = acc[0][reg] + bs_[0] + deg * bv_[0];
    float fv = acc[1][reg] + bs_[1] + deg * bv_[1];
    float gv = acc[2][reg] + bs_[2] + deg * bv_[2];
    float ov = acc[3][reg] + bs_[3] + deg * bv_[3];
    float cn = sigm(fv) * co + sigm(iv) * tanh_(gv);
    hL[(size_t)row * DD + cw] = cn;
    Lbuf[(size_t)row * DD + cw] = sigm(ov) * tanh_(cn);
  }
}

__device__ __forceinline__ void clause_f2_tile(
    SmemU& sm, int tile,
    const float* __restrict__ Lbuf, const int* __restrict__ csc, const int* __restrict__ ccnt,
    const unsigned short* __restrict__ qkhi, const unsigned short* __restrict__ qklo,
    const float* __restrict__ bsum, const float* __restrict__ bvec,
    float* __restrict__ hC, float* __restrict__ Cs) {
  unsigned short* A = sm.cf2.A;
  int* IDX = sm.cf2.IDX;
  const int t = threadIdx.x;
  const int rowBase = tile * 32;

  ((int4*)IDX)[t] = ((const int4*)(csc + rowBase * COLW))[t];
  __syncthreads();

  {
    const int r = t >> 4, sub = t & 15;
    const int c = rowBase + r;
    int cnt = ccnt[c]; if (cnt > COLW) cnt = COLW;
    const int* lst = IDX + r * COLW;
    float4 a0 = make_float4(0, 0, 0, 0), a1 = a0;
    int j = 0;
    for (; j + 8 <= cnt; j += 8) {
      float4 p0[8], p1[8];
      #pragma unroll
      for (int u = 0; u < 8; ++u) {
        const float4* s4 = (const float4*)(Lbuf + (size_t)lst[j + u] * DD) + sub * 2;
        p0[u] = s4[0]; p1[u] = s4[1];
      }
      #pragma unroll
      for (int u = 0; u < 8; ++u) { add4(a0, p0[u]); add4(a1, p1[u]); }
    }
    for (; j < cnt; ++j) {
      const float4* s4 = (const float4*)(Lbuf + (size_t)lst[j] * DD) + sub * 2;
      add4(a0, s4[0]); add4(a1, s4[1]);
    }
    store_oct2g(A, OS, SPLIT, sub, r, a0, a1);
    const float4* h4 = (const float4*)(hC + (size_t)c * DD) + sub * 2;
    store_oct2g(A, OS, SPLIT, 16 + sub, r, h4[0], h4[1]);
  }
  __syncthreads();

  const int w = t >> 6, l = t & 63;
  const int quad = l >> 4, lane16 = l & 15;
  const int cw = w * 16 + lane16;
  f32x4 acc[2][4];
  #pragma unroll
  for (int mt = 0; mt < 2; ++mt)
    #pragma unroll
    for (int g = 0; g < 4; ++g) acc[mt][g] = (f32x4){0.f, 0.f, 0.f, 0.f};

  const half8* As = (const half8*)A;
  const half8* Bh = (const half8*)qkhi;
  const half8* Bl = (const half8*)qklo;

  __builtin_amdgcn_s_setprio(1);   // T5
  #pragma unroll
  for (int s = 0; s < 8; ++s) {
    int ao = (s * 4 + quad) * OS + lane16;
    half8 a0h = As[ao],           a1h = As[ao + 16];
    half8 a0l = As[SPLITS8 + ao], a1l = As[SPLITS8 + ao + 16];
    int bo = (s * 4 + quad) * 512 + cw;
    #pragma unroll
    for (int g = 0; g < 4; ++g) {
      half8 bh = Bh[bo + g * 128];
      half8 bl = Bl[bo + g * 128];
      MFMA4(acc[0][g], a0h, a0l, bh, bl);
      MFMA4(acc[1][g], a1h, a1l, bh, bl);
    }
  }
  __builtin_amdgcn_s_setprio(0);
  clause_epilogue(acc, bsum, bvec, ccnt, hC, Cs, rowBase, quad, cw);
}

__device__ __forceinline__ void literal_f2_tile(
    SmemU& sm, int tile,
    const float* __restrict__ Cs, const int* __restrict__ csr, const int* __restrict__ rcnt,
    const unsigned short* __restrict__ qkhi, const unsigned short* __restrict__ qklo,
    const float* __restrict__ bsum, const float* __restrict__ bvec,
    float* __restrict__ hL, float* __restrict__ Lbuf) {
  unsigned short* A = sm.lf2.A;
  int* IDX = sm.lf2.IDX;
  const int t = threadIdx.x;
  const int rowBase = tile * 32;

  ((int4*)IDX)[t] = ((const int4*)(csr + rowBase * ROWW))[t];
  if (t < 256) ((int4*)IDX)[t + 512] = ((const int4*)(csr + rowBase * ROWW))[t + 512];
  __syncthreads();

  { // gather + stage: 16 threads/row, 8 floats each; K = [msgs | L | hL]
    const int r = t >> 4, sub = t & 15;
    const int lr = rowBase + r;
    int cnt = rcnt[lr]; if (cnt > ROWW) cnt = ROWW;
    const int* lst = IDX + r * ROWW;
    float4 a0 = make_float4(0, 0, 0, 0), a1 = a0;
    int j = 0;
    for (; j + 8 <= cnt; j += 8) {
      float4 p0[8], p1[8];
      #pragma unroll
      for (int u = 0; u < 8; ++u) {
        const float4* s4 = (const float4*)(Cs + (size_t)lst[j + u] * DD) + sub * 2;
        p0[u] = s4[0]; p1[u] = s4[1];
      }
      #pragma unroll
      for (int u = 0; u < 8; ++u) { add4(a0, p0[u]); add4(a1, p1[u]); }
    }
    for (; j < cnt; ++j) {
      const float4* s4 = (const float4*)(Cs + (size_t)lst[j] * DD) + sub * 2;
      add4(a0, s4[0]); add4(a1, s4[1]);
    }
    store_oct2g(A, L2S, L2SPL, sub, r, a0, a1);
    const float4* l4 = (const float4*)(Lbuf + (size_t)lr * DD) + sub * 2;
    store_oct2g(A, L2S, L2SPL, 16 + sub, r, l4[0], l4[1]);
    const float4* h4 = (const float4*)(hL + (size_t)lr * DD) + sub * 2;
    store_oct2g(A, L2S, L2SPL, 32 + sub, r, h4[0], h4[1]);
  }
  __syncthreads();

  const int w = t >> 6, l = t & 63;
  const int quad = l >> 4, lane16 = l & 15;
  const int cw = w * 16 + lane16;
  f32x4 acc[2][4];
  #pragma unroll
  for (int mt = 0; mt < 2; ++mt)
    #pragma unroll
    for (int g = 0; g < 4; ++g) acc[mt][g] = (f32x4){0.f, 0.f, 0.f, 0.f};

  const half8* As = (const half8*)A;        // idx = oct*L2S + m
  const half8* Bh = (const half8*)qkhi;
  const half8* Bl = (const half8*)qklo;

  __builtin_amdgcn_s_setprio(1);   // T5
  #pragma unroll
  for (int s = 0; s < 12; ++s) {            // K=384
    int ao = (s * 4 + quad) * L2S + lane16;
    half8 a0h = As[ao],             a1h = As[ao + 16];
    half8 a0l = As[L2SPL / 8 + ao], a1l = As[L2SPL / 8 + ao + 16];
    int bo = (s * 4 + quad) * 512 + cw;
    #pragma unroll
    for (int g = 0; g < 4; ++g) {
      half8 bh = Bh[bo + g * 128];
      half8 bl = Bl[bo + g * 128];
      MFMA4(acc[0][g], a0h, a0l, bh, bl);
      MFMA4(acc[1][g], a1h, a1l, bh, bl);
    }
  }
  __builtin_amdgcn_s_setprio(0);
  literal_epilogue2(acc, bsum, bvec, rcnt, hL, Lbuf, rowBase, quad, cw);
}

// ---------------- the persistent cooperative mega-kernel ----------------
// R5 theory: the ~750 us unexplained by bottom-up kernel models is the 22
// stream-serialized dispatch boundaries (end-drain + per-XCD cache ops + CP +
// ramp ~ 30-40 us each on 8 XCDs). Fuse everything into ONE cooperative launch;
// phases separated by device-fence + grid.sync (18 syncs @ ~2-5 us).

struct MegaArgs {
  const float *L0, *hL0, *hC0;
  const float4 *M4;
  const float *Wlc, *blc, *Wcl, *bcl;
  const float *WihC, *WhhC, *bihC, *bhhC;
  const float *WihL, *WhhL, *bihL, *bhhL;
  float *hL, *hC, *Cs, *bsumC, *bvecC, *bsumL, *bvecL;
  unsigned short *pkChi, *pkCmd, *pkClo, *pkLhi, *pkLmd, *pkLlo;
  unsigned short *qkChi, *qkClo, *qkLhi, *qkLlo;
  int *csr, *csc, *rcnt, *ccnt;
  float *Lbuf;
};

#define GSYNC() do { __threadfence(); grid.sync(); } while (0)

__global__ __launch_bounds__(512, 2) void mega(MegaArgs a) {
  __shared__ SmemU sm;
  cg::grid_group grid = cg::this_grid();
  const int gtid = blockIdx.x * 512 + threadIdx.x;
  const int gstride = GRID * 512;

  // ---- phase: init states + zero counters (replaces init_states + memset) ----
  for (int j = gtid; j < NL * DD / 4; j += gstride) {
    ((float4*)a.Lbuf)[j] = ((const float4*)a.L0)[j];
    ((float4*)a.hL)[j]   = ((const float4*)a.hL0)[j];
  }
  for (int j = gtid; j < NC * DD / 4; j += gstride)
    ((float4*)a.hC)[j] = ((const float4*)a.hC0)[j];
  for (int j = gtid; j < NL + NC; j += gstride) a.rcnt[j] = 0;  // rcnt|ccnt contiguous
  GSYNC();

  // ---- phase: scan_M (padded-ELL both directions) ----
  {
    const int total = (NL * NC) / 4;
    for (int i = gtid; i < total; i += gstride) {
      float4 v = a.M4[i];
      if (v.x == 0.f && v.y == 0.f && v.z == 0.f && v.w == 0.f) continue;
      int base = i * 4;
      int l = base / NC;
      int c0 = base - l * NC;
      float vv[4] = {v.x, v.y, v.z, v.w};
      #pragma unroll
      for (int e = 0; e < 4; ++e) {
        if (vv[e] != 0.f) {
          int c = c0 + e;
          int rp = atomicAdd(&a.rcnt[l], 1);
          if (rp < ROWW) a.csr[l * ROWW + rp] = c;
          int cp = atomicAdd(&a.ccnt[c], 1);
          if (cp < COLW) a.csc[c * COLW + cp] = l;
        }
      }
    }
  }
  GSYNC();

  // ---- phase: build packs + biases (independent outputs) ----
  for (int i = gtid; i < 256 * 512; i += gstride) {   // clause pack
    int k = i >> 9, n = i & 511;
    float w;
    if (k < 128) {
      float s = 0.f;
      for (int d = 0; d < 128; ++d) s += a.WihC[n * 128 + d] * a.Wlc[d * 128 + k];
      w = s;
    } else {
      w = a.WhhC[n * 128 + (k - 128)];
    }
    int idx = ((k >> 3) * 512 + n) * 8 + (k & 7);
    split_store_bf3(w, idx, a.pkChi, a.pkCmd, a.pkClo);
    splitf16(w, a.qkChi[idx], a.qkClo[idx]);
  }
  for (int i = gtid; i < 384 * 512; i += gstride) {   // literal pack
    int k = i >> 9, n = i & 511;
    float w;
    if (k < 128) {
      float s = 0.f;
      for (int d = 0; d < 128; ++d) s += a.WihL[n * 256 + d] * a.Wcl[d * 128 + k];
      w = s;
    } else if (k < 256) {
      w = a.WihL[n * 256 + k];
    } else {
      w = a.WhhL[n * 128 + (k - 256)];
    }
    int idx = ((k >> 3) * 512 + n) * 8 + (k & 7);
    split_store_bf3(w, idx, a.pkLhi, a.pkLmd, a.pkLlo);
    splitf16(w, a.qkLhi[idx], a.qkLlo[idx]);
  }
  if (gtid < 1024) {   // biases
    int i = gtid;
    if (i < 512) {
      a.bsumC[i] = a.bihC[i] + a.bhhC[i];
      float s = 0.f;
      for (int d = 0; d < 128; ++d) s += a.WihC[i * 128 + d] * a.blc[d];
      a.bvecC[i] = s;
    } else {
      int n = i - 512;
      a.bsumL[n] = a.bihL[n] + a.bhhL[n];
      float s = 0.f;
      for (int d = 0; d < 128; ++d) s += a.WihL[n * 256 + d] * a.bcl[d];
      a.bvecL[n] = s;
    }
  }
  GSYNC();

  // ---- step 0: hidden states zero -> truncated K (exactly equivalent) ----
  for (int tile = blockIdx.x; tile < NC / 32; tile += GRID)
    clause_bf3_tile<16, false>(sm, tile, a.Lbuf, a.csc, a.ccnt,
                               a.pkChi, a.pkCmd, a.pkClo, a.bsumC, a.bvecC, a.hC, a.Cs);
  GSYNC();
  for (int tile = blockIdx.x; tile < NL / 16; tile += GRID)
    literal_bf3_tile<32, false>(sm, tile, a.Cs, a.csr, a.rcnt,
                                a.pkLhi, a.pkLmd, a.pkLlo, a.bsumL, a.bvecL, a.hL, a.Lbuf);
  GSYNC();

  // ---- step 1 (bf16, full K) ----
  for (int tile = blockIdx.x; tile < NC / 32; tile += GRID)
    clause_bf3_tile<32, true>(sm, tile, a.Lbuf, a.csc, a.ccnt,
                              a.pkChi, a.pkCmd, a.pkClo, a.bsumC, a.bvecC, a.hC, a.Cs);
  GSYNC();
  for (int tile = blockIdx.x; tile < NL / 16; tile += GRID)
    literal_bf3_tile<48, true>(sm, tile, a.Cs, a.csr, a.rcnt,
                               a.pkLhi, a.pkLmd, a.pkLlo, a.bsumL, a.bvecL, a.hL, a.Lbuf);
  GSYNC();

  // ---- steps 2..7 (fp16) ----
  for (int st = NBF; st < TSTEPS; ++st) {
    for (int tile = blockIdx.x; tile < NC / 32; tile += GRID)
      clause_f2_tile(sm, tile, a.Lbuf, a.csc, a.ccnt,
                     a.qkChi, a.qkClo, a.bsumC, a.bvecC, a.hC, a.Cs);
    GSYNC();
    for (int tile = blockIdx.x; tile < NL / 32; tile += GRID)
      literal_f2_tile(sm, tile, a.Cs, a.csr, a.rcnt,
                      a.qkLhi, a.qkLlo, a.bsumL, a.bvecL, a.hL, a.Lbuf);
    if (st != TSTEPS - 1) GSYNC();
  }
}

// ---------------- launch ----------------

extern "C" void kernel_launch(void* const* d_in, const int* in_sizes, int n_in,
                              void* d_out, int out_size, void* d_ws, size_t ws_size,
                              hipStream_t stream) {
  const float* L0   = (const float*)d_in[0];
  // d_in[1] = C_state (unused), d_in[5] = n_vars (flip is identity)
  const float* hL0  = (const float*)d_in[2];
  const float* hC0  = (const float*)d_in[3];
  const float* M    = (const float*)d_in[4];
  const float* Wlc  = (const float*)d_in[6];
  const float* blc  = (const float*)d_in[7];
  const float* Wcl  = (const float*)d_in[8];
  const float* bcl  = (const float*)d_in[9];
  const float* WihC = (const float*)d_in[10];
  const float* WhhC = (const float*)d_in[11];
  const float* bihC = (const float*)d_in[12];
  const float* bhhC = (const float*)d_in[13];
  const float* WihL = (const float*)d_in[14];
  const float* WhhL = (const float*)d_in[15];
  const float* bihL = (const float*)d_in[16];
  const float* bhhL = (const float*)d_in[17];

  float* ws    = (float*)d_ws;
  float* hL    = ws;                         // NL*DD
  float* hC    = hL + NL * DD;               // NC*DD
  float* Cs    = hC + NC * DD;               // NC*DD
  float* bsumC = Cs + NC * DD;               // 512 each
  float* bvecC = bsumC + 512;
  float* bsumL = bvecC + 512;
  float* bvecL = bsumL + 512;
  unsigned short* pkChi = (unsigned short*)(bvecL + 512);   // bf16 clause: 3 x 256*512
  unsigned short* pkCmd = pkChi + 256 * 512;
  unsigned short* pkClo = pkCmd + 256 * 512;
  unsigned short* pkLhi = pkClo + 256 * 512;                // bf16 literal: 3 x 384*512
  unsigned short* pkLmd = pkLhi + 384 * 512;
  unsigned short* pkLlo = pkLmd + 384 * 512;
  unsigned short* qkChi = pkLlo + 384 * 512;                // fp16 clause: 2 x 256*512
  unsigned short* qkClo = qkChi + 256 * 512;
  unsigned short* qkLhi = qkClo + 256 * 512;                // fp16 literal: 2 x 384*512
  unsigned short* qkLlo = qkLhi + 384 * 512;
  int* csr  = (int*)(qkLlo + 384 * 512);     // NL*ROWW
  int* csc  = csr + NL * ROWW;               // NC*COLW
  int* rcnt = csc + NC * COLW;               // NL
  int* ccnt = rcnt + NL;                     // NC (contiguous with rcnt)
  float* Lbuf = (float*)d_out;               // literal state lives in d_out

  MegaArgs args;
  args.L0 = L0; args.hL0 = hL0; args.hC0 = hC0; args.M4 = (const float4*)M;
  args.Wlc = Wlc; args.blc = blc; args.Wcl = Wcl; args.bcl = bcl;
  args.WihC = WihC; args.WhhC = WhhC; args.bihC = bihC; args.bhhC = bhhC;
  args.WihL = WihL; args.WhhL = WhhL; args.bihL = bihL; args.bhhL = bhhL;
  args.hL = hL; args.hC = hC; args.Cs = Cs;
  args.bsumC = bsumC; args.bvecC = bvecC; args.bsumL = bsumL; args.bvecL = bvecL;
  args.pkChi = pkChi; args.pkCmd = pkCmd; args.pkClo = pkClo;
  args.pkLhi = pkLhi; args.pkLmd = pkLmd; args.pkLlo = pkLlo;
  args.qkChi = qkChi; args.qkClo = qkClo; args.qkLhi = qkLhi; args.qkLlo = qkLlo;
  args.csr = csr; args.csc = csc; args.rcnt = rcnt; args.ccnt = ccnt;
  args.Lbuf = Lbuf;

  void* kp[] = {(void*)&args};
  hipLaunchCooperativeKernel((const void*)mega, dim3(GRID), dim3(512), kp, 0, stream);
}

// Round 7
// 1426.419 us; speedup vs baseline: 2.2118x; 2.2118x over previous
//
#include <hip/hip_runtime.h>

#define DD   128
#define NL   8000
#define NC   16000
#define TSTEPS 8
#define NBF  2     // steps 0..1 bf16 6-term; steps 2..7 fp16 4-term
#define ROWW 96    // max clauses per literal (mean 40, std 6.3)
#define COLW 64    // max literals per clause (mean 20, std 4.4)

// R6: all step kernels use 256-thread blocks, 16-row tiles, stride-17 LDS.
// Mega-kernel counters (R5) showed MfmaUtil 3.8% / VALUBusy 4.8% / HBM 8% /
// FETCH 1.38 GB total -> latency-bound, caches serve everything. The lever is
// co-resident independent blocks per CU: 2 -> 4 (launch_bounds(256,4), small LDS).
#define S16  17                  // short8 slots per oct (16 rows + 1 pad)
#define CP16 (32 * S16 * 8)      // clause plane shorts (K=256, 32 octs) = 4352
#define LP16 (48 * S16 * 8)      // literal plane shorts (K=384, 48 octs) = 6528

typedef __attribute__((ext_vector_type(8))) short  short8;
typedef __attribute__((ext_vector_type(8))) _Float16 half8;
typedef __attribute__((ext_vector_type(4))) float  f32x4;

__device__ __forceinline__ float frcp(float x) { return __builtin_amdgcn_rcpf(x); }
__device__ __forceinline__ float sigm(float x) { return frcp(1.f + __expf(-x)); }
__device__ __forceinline__ float tanh_(float x) {
  float e = __expf(2.f * x);
  return 1.f - 2.f * frcp(e + 1.f);
}
__device__ __forceinline__ void add4(float4& a, const float4 b) {
  a.x += b.x; a.y += b.y; a.z += b.z; a.w += b.w;
}
__device__ __forceinline__ unsigned short bfround(float v) {  // RNE fp32 -> bf16
  unsigned u = __float_as_uint(v);
  return (unsigned short)((u + 0x7FFF + ((u >> 16) & 1)) >> 16);
}
__device__ __forceinline__ float bf2f(unsigned short b) {
  return __uint_as_float(((unsigned)b) << 16);
}
__device__ __forceinline__ void splitf16(float v, unsigned short& h, unsigned short& l) {
  _Float16 hh = (_Float16)v;           // RNE
  float r = v - (float)hh;             // exact
  _Float16 ll = (_Float16)r;
  h = __builtin_bit_cast(unsigned short, hh);
  l = __builtin_bit_cast(unsigned short, ll);
}
__device__ __forceinline__ int4 packi4(const unsigned short* p) {
  return make_int4(p[0] | ((int)p[1] << 16), p[2] | ((int)p[3] << 16),
                   p[4] | ((int)p[5] << 16), p[6] | ((int)p[7] << 16));
}

// bf16 triple-split 8 floats -> 3 octets, generic layout (strideS8 slots, plane shorts)
__device__ __forceinline__ void store_oct3g(unsigned short* A, int strideS8, int planeShorts,
                                            int oct, int m, float4 a, float4 b) {
  float f[8] = {a.x, a.y, a.z, a.w, b.x, b.y, b.z, b.w};
  unsigned short h[8], md[8], lo[8];
  #pragma unroll
  for (int j = 0; j < 8; ++j) {
    h[j] = bfround(f[j]);
    float r1 = f[j] - bf2f(h[j]);       // exact (Sterbenz)
    md[j] = bfround(r1);
    float r2 = r1 - bf2f(md[j]);        // exact
    lo[j] = bfround(r2);
  }
  int base = (oct * strideS8 + m) * 8;
  *(int4*)(A + base)                   = packi4(h);
  *(int4*)(A + planeShorts + base)     = packi4(md);
  *(int4*)(A + 2 * planeShorts + base) = packi4(lo);
}

// fp16 2-split 8 floats -> 2 octets, generic layout
__device__ __forceinline__ void store_oct2g(unsigned short* A, int strideS8, int plane,
                                            int oct, int m, float4 a, float4 b) {
  float f[8] = {a.x, a.y, a.z, a.w, b.x, b.y, b.z, b.w};
  unsigned short h[8], lo[8];
  #pragma unroll
  for (int j = 0; j < 8; ++j) splitf16(f[j], h[j], lo[j]);
  int base = (oct * strideS8 + m) * 8;
  *(int4*)(A + base)         = packi4(h);
  *(int4*)(A + plane + base) = packi4(lo);
}

// 6-term bf16 triple-split product (error ~2^-27)
#define MFMA6(ACC, AH, AM, AL, BH, BM, BL)                                   \
  ACC = __builtin_amdgcn_mfma_f32_16x16x32_bf16(AH, BH, ACC, 0, 0, 0);       \
  ACC = __builtin_amdgcn_mfma_f32_16x16x32_bf16(AH, BM, ACC, 0, 0, 0);       \
  ACC = __builtin_amdgcn_mfma_f32_16x16x32_bf16(AM, BH, ACC, 0, 0, 0);       \
  ACC = __builtin_amdgcn_mfma_f32_16x16x32_bf16(AH, BL, ACC, 0, 0, 0);       \
  ACC = __builtin_amdgcn_mfma_f32_16x16x32_bf16(AL, BH, ACC, 0, 0, 0);       \
  ACC = __builtin_amdgcn_mfma_f32_16x16x32_bf16(AM, BM, ACC, 0, 0, 0);

// 4-term fp16 2-split product (error ~2^-22 rep residual)
#define MFMA4(ACC, AH, AL, BH, BL)                                           \
  ACC = __builtin_amdgcn_mfma_f32_16x16x32_f16(AH, BH, ACC, 0, 0, 0);        \
  ACC = __builtin_amdgcn_mfma_f32_16x16x32_f16(AH, BL, ACC, 0, 0, 0);        \
  ACC = __builtin_amdgcn_mfma_f32_16x16x32_f16(AL, BH, ACC, 0, 0, 0);        \
  ACC = __builtin_amdgcn_mfma_f32_16x16x32_f16(AL, BL, ACC, 0, 0, 0);

// ---------------- preprocessing (unchanged, proven) ----------------

__global__ __launch_bounds__(256) void init_states(
    float4* __restrict__ Lbuf, const float4* __restrict__ L0,
    float4* __restrict__ hL, const float4* __restrict__ hL0,
    float4* __restrict__ hC, const float4* __restrict__ hC0) {
  int i = blockIdx.x * 256 + threadIdx.x, stride = gridDim.x * 256;
  for (int j = i; j < NL * DD / 4; j += stride) { Lbuf[j] = L0[j]; hL[j] = hL0[j]; }
  for (int j = i; j < NC * DD / 4; j += stride) hC[j] = hC0[j];
}

// one pass over M (512 MB): padded-ELL both directions
__global__ __launch_bounds__(256) void scan_M(const float4* __restrict__ M4,
                                              int* __restrict__ csr, int* __restrict__ csc,
                                              int* __restrict__ rcnt, int* __restrict__ ccnt) {
  const int total = (NL * NC) / 4;
  int stride = gridDim.x * blockDim.x;
  for (int i = blockIdx.x * blockDim.x + threadIdx.x; i < total; i += stride) {
    float4 v = M4[i];
    if (v.x == 0.f && v.y == 0.f && v.z == 0.f && v.w == 0.f) continue;
    int base = i * 4;
    int l = base / NC;
    int c0 = base - l * NC;
    float vv[4] = {v.x, v.y, v.z, v.w};
    #pragma unroll
    for (int e = 0; e < 4; ++e) {
      if (vv[e] != 0.f) {
        int c = c0 + e;
        int rp = atomicAdd(&rcnt[l], 1);
        if (rp < ROWW) csr[l * ROWW + rp] = c;
        int cp = atomicAdd(&ccnt[c], 1);
        if (cp < COLW) csc[c * COLW + cp] = l;
      }
    }
  }
}

__device__ __forceinline__ void split_store_bf3(float w, int idx, unsigned short* hi,
                                                unsigned short* md, unsigned short* lo) {
  unsigned short h = bfround(w);
  float r1 = w - bf2f(h);
  unsigned short m = bfround(r1);
  float r2 = r1 - bf2f(m);
  hi[idx] = h; md[idx] = m; lo[idx] = bfround(r2);
}

// combined clause weights B[k][n]: k<128: sum_d WihC[n,d]*Wlc[d,k]; k>=128: WhhC[n,k-128]
__global__ __launch_bounds__(256) void build_packC(
    const float* __restrict__ WihC, const float* __restrict__ Wlc, const float* __restrict__ WhhC,
    unsigned short* __restrict__ pkhi, unsigned short* __restrict__ pkmd, unsigned short* __restrict__ pklo,
    unsigned short* __restrict__ qkhi, unsigned short* __restrict__ qklo) {
  int i = blockIdx.x * 256 + threadIdx.x;   // [0, 256*512)
  int k = i >> 9, n = i & 511;
  float w;
  if (k < 128) {
    float s = 0.f;
    for (int d = 0; d < 128; ++d) s += WihC[n * 128 + d] * Wlc[d * 128 + k];
    w = s;
  } else {
    w = WhhC[n * 128 + (k - 128)];
  }
  int idx = ((k >> 3) * 512 + n) * 8 + (k & 7);
  split_store_bf3(w, idx, pkhi, pkmd, pklo);
  splitf16(w, qkhi[idx], qklo[idx]);
}

// literal B[k][n]: k<128: sum_d WihL[n,d]*Wcl[d,k]; 128..255: WihL[n,k]; 256..383: WhhL[n,k-256]
__global__ __launch_bounds__(256) void build_packL(
    const float* __restrict__ WihL, const float* __restrict__ Wcl, const float* __restrict__ WhhL,
    unsigned short* __restrict__ pkhi, unsigned short* __restrict__ pkmd, unsigned short* __restrict__ pklo,
    unsigned short* __restrict__ qkhi, unsigned short* __restrict__ qklo) {
  int i = blockIdx.x * 256 + threadIdx.x;   // [0, 384*512)
  int k = i >> 9, n = i & 511;
  float w;
  if (k < 128) {
    float s = 0.f;
    for (int d = 0; d < 128; ++d) s += WihL[n * 256 + d] * Wcl[d * 128 + k];
    w = s;
  } else if (k < 256) {
    w = WihL[n * 256 + k];
  } else {
    w = WhhL[n * 128 + (k - 256)];
  }
  int idx = ((k >> 3) * 512 + n) * 8 + (k & 7);
  split_store_bf3(w, idx, pkhi, pkmd, pklo);
  splitf16(w, qkhi[idx], qklo[idx]);
}

__global__ __launch_bounds__(256) void build_bias(
    const float* __restrict__ bihC, const float* __restrict__ bhhC,
    const float* __restrict__ WihC, const float* __restrict__ blc,
    const float* __restrict__ bihL, const float* __restrict__ bhhL,
    const float* __restrict__ WihL, const float* __restrict__ bcl,
    float* __restrict__ bsumC, float* __restrict__ bvecC,
    float* __restrict__ bsumL, float* __restrict__ bvecL) {
  int i = blockIdx.x * 256 + threadIdx.x;   // [0, 1024)
  if (i < 512) {
    bsumC[i] = bihC[i] + bhhC[i];
    float s = 0.f;
    for (int d = 0; d < 128; ++d) s += WihC[i * 128 + d] * blc[d];
    bvecC[i] = s;
  } else if (i < 1024) {
    int n = i - 512;
    bsumL[n] = bihL[n] + bhhL[n];
    float s = 0.f;
    for (int d = 0; d < 128; ++d) s += WihL[n * 256 + d] * bcl[d];
    bvecL[n] = s;
  }
}

// ---------------- 16-row epilogues ----------------
// acc[g2] holds cols g2*64+cw; gate g at dcol dc=h*64+cw lives in acc[2g+h].
__device__ __forceinline__ void clause_epi16(
    const f32x4 acc[8], const float* bsum, const float* bvec, const int* ccnt,
    float* hC, float* Cs, int rowBase, int quad, int cw) {
  #pragma unroll
  for (int h = 0; h < 2; ++h) {
    int dc = h * 64 + cw;
    float bs_[4], bv_[4];
    #pragma unroll
    for (int g = 0; g < 4; ++g) { bs_[g] = bsum[g * 128 + dc]; bv_[g] = bvec[g * 128 + dc]; }
    #pragma unroll
    for (int reg = 0; reg < 4; ++reg) {
      int row = rowBase + quad * 4 + reg;
      float deg = (float)ccnt[row];
      float co = hC[(size_t)row * DD + dc];
      float iv = acc[0 + h][reg] + bs_[0] + deg * bv_[0];
      float fv = acc[2 + h][reg] + bs_[1] + deg * bv_[1];
      float gv = acc[4 + h][reg] + bs_[2] + deg * bv_[2];
      float ov = acc[6 + h][reg] + bs_[3] + deg * bv_[3];
      float cn = sigm(fv) * co + sigm(iv) * tanh_(gv);
      hC[(size_t)row * DD + dc] = cn;
      Cs[(size_t)row * DD + dc] = sigm(ov) * tanh_(cn);
    }
  }
}

__device__ __forceinline__ void literal_epi16(
    const f32x4 acc[8], const float* bsum, const float* bvec, const int* rcnt,
    float* hL, float* Lbuf, int rowBase, int quad, int cw) {
  #pragma unroll
  for (int h = 0; h < 2; ++h) {
    int dc = h * 64 + cw;
    float bs_[4], bv_[4];
    #pragma unroll
    for (int g = 0; g < 4; ++g) { bs_[g] = bsum[g * 128 + dc]; bv_[g] = bvec[g * 128 + dc]; }
    #pragma unroll
    for (int reg = 0; reg < 4; ++reg) {
      int row = rowBase + quad * 4 + reg;
      float deg = (float)rcnt[row];
      float co = hL[(size_t)row * DD + dc];
      float iv = acc[0 + h][reg] + bs_[0] + deg * bv_[0];
      float fv = acc[2 + h][reg] + bs_[1] + deg * bv_[1];
      float gv = acc[4 + h][reg] + bs_[2] + deg * bv_[2];
      float ov = acc[6 + h][reg] + bs_[3] + deg * bv_[3];
      float cn = sigm(fv) * co + sigm(iv) * tanh_(gv);
      hL[(size_t)row * DD + dc] = cn;
      Lbuf[(size_t)row * DD + dc] = sigm(ov) * tanh_(cn);
    }
  }
}

// ---------------- bf16 6-term step kernels (steps 0..NBF-1) ----------------
// 256 threads, 16-row tiles: LDS 26-39 KB -> 4 blocks/CU (launch_bounds(256,4),
// VGPR<=128). Per-element summation order identical to the 512-thread version
// (same 16-threads/row gather, same K-oct order, same MFMA term order).

template <int NOCT, bool STAGE_H>
__global__ __launch_bounds__(256, 4) void clause_bf3(
    const float* __restrict__ Lbuf, const int* __restrict__ csc, const int* __restrict__ ccnt,
    const unsigned short* __restrict__ pkhi, const unsigned short* __restrict__ pkmd,
    const unsigned short* __restrict__ pklo,
    const float* __restrict__ bsum, const float* __restrict__ bvec,
    float* __restrict__ hC, float* __restrict__ Cs) {
  __shared__ unsigned short A[3 * CP16];    // 26,112 B
  __shared__ int IDX[16 * COLW];            // 4 KB
  const int t = threadIdx.x;
  const int rowBase = blockIdx.x * 16;

  ((int4*)IDX)[t] = ((const int4*)(csc + rowBase * COLW))[t];   // 256 int4
  __syncthreads();

  { // gather + stage: 16 threads/row, 8 floats each; K = [msgs | hC?]
    const int r = t >> 4, sub = t & 15;
    const int c = rowBase + r;
    int cnt = ccnt[c]; if (cnt > COLW) cnt = COLW;
    const int* lst = IDX + r * COLW;
    float4 a0 = make_float4(0, 0, 0, 0), a1 = a0;
    int j = 0;
    for (; j + 8 <= cnt; j += 8) {
      float4 p0[8], p1[8];
      #pragma unroll
      for (int u = 0; u < 8; ++u) {
        const float4* s4 = (const float4*)(Lbuf + (size_t)lst[j + u] * DD) + sub * 2;
        p0[u] = s4[0]; p1[u] = s4[1];
      }
      #pragma unroll
      for (int u = 0; u < 8; ++u) { add4(a0, p0[u]); add4(a1, p1[u]); }
    }
    for (; j < cnt; ++j) {
      const float4* s4 = (const float4*)(Lbuf + (size_t)lst[j] * DD) + sub * 2;
      add4(a0, s4[0]); add4(a1, s4[1]);
    }
    store_oct3g(A, S16, CP16, sub, r, a0, a1);
    if constexpr (STAGE_H) {
      const float4* h4 = (const float4*)(hC + (size_t)c * DD) + sub * 2;
      store_oct3g(A, S16, CP16, 16 + sub, r, h4[0], h4[1]);
    }
  }
  __syncthreads();

  const int w = t >> 6, l = t & 63;
  const int quad = l >> 4, lane16 = l & 15;
  const int cw = w * 16 + lane16;           // 0..63
  f32x4 acc[8];
  #pragma unroll
  for (int g2 = 0; g2 < 8; ++g2) acc[g2] = (f32x4){0.f, 0.f, 0.f, 0.f};

  const short8* As = (const short8*)A;
  const short8* Bh = (const short8*)pkhi;
  const short8* Bm = (const short8*)pkmd;
  const short8* Bl = (const short8*)pklo;

  __builtin_amdgcn_s_setprio(1);   // T5 (R2: +1.2%)
  #pragma unroll
  for (int s = 0; s < NOCT / 4; ++s) {
    int ao = (s * 4 + quad) * S16 + lane16;
    short8 ah = As[ao];
    short8 am = As[CP16 / 8 + ao];
    short8 al = As[2 * (CP16 / 8) + ao];
    int bo = (s * 4 + quad) * 512 + cw;
    #pragma unroll
    for (int g2 = 0; g2 < 8; ++g2) {
      short8 bh = Bh[bo + g2 * 64];
      short8 bm = Bm[bo + g2 * 64];
      short8 bl = Bl[bo + g2 * 64];
      MFMA6(acc[g2], ah, am, al, bh, bm, bl);
    }
  }
  __builtin_amdgcn_s_setprio(0);
  clause_epi16(acc, bsum, bvec, ccnt, hC, Cs, rowBase, quad, cw);
}

// literal bf16: 256 threads, 16-row tiles, no IDX LDS (csr reads broadcast;
// LDS 39,168 B -> exactly 4 blocks/CU at 156.7 KB).
template <int NOCT, bool STAGE_H>
__global__ __launch_bounds__(256, 4) void literal_bf3(
    const float* __restrict__ Cs, const int* __restrict__ csr, const int* __restrict__ rcnt,
    const unsigned short* __restrict__ pkhi, const unsigned short* __restrict__ pkmd,
    const unsigned short* __restrict__ pklo,
    const float* __restrict__ bsum, const float* __restrict__ bvec,
    float* __restrict__ hL, float* __restrict__ Lbuf) {
  __shared__ unsigned short A[3 * LP16];    // 39,168 B
  const int t = threadIdx.x;
  const int rowBase = blockIdx.x * 16;

  { // gather + stage: 16 threads/row, 8 floats each; K = [msgs | L | hL?]
    const int r = t >> 4, sub = t & 15;
    const int lr = rowBase + r;
    int cnt = rcnt[lr]; if (cnt > ROWW) cnt = ROWW;
    const int* lst = csr + lr * ROWW;
    float4 a0 = make_float4(0, 0, 0, 0), a1 = a0;
    int j = 0;
    for (; j + 8 <= cnt; j += 8) {
      float4 p0[8], p1[8];
      #pragma unroll
      for (int u = 0; u < 8; ++u) {
        const float4* s4 = (const float4*)(Cs + (size_t)lst[j + u] * DD) + sub * 2;
        p0[u] = s4[0]; p1[u] = s4[1];
      }
      #pragma unroll
      for (int u = 0; u < 8; ++u) { add4(a0, p0[u]); add4(a1, p1[u]); }
    }
    for (; j < cnt; ++j) {
      const float4* s4 = (const float4*)(Cs + (size_t)lst[j] * DD) + sub * 2;
      add4(a0, s4[0]); add4(a1, s4[1]);
    }
    store_oct3g(A, S16, LP16, sub, r, a0, a1);
    const float4* l4 = (const float4*)(Lbuf + (size_t)lr * DD) + sub * 2;
    store_oct3g(A, S16, LP16, 16 + sub, r, l4[0], l4[1]);
    if constexpr (STAGE_H) {
      const float4* h4 = (const float4*)(hL + (size_t)lr * DD) + sub * 2;
      store_oct3g(A, S16, LP16, 32 + sub, r, h4[0], h4[1]);
    }
  }
  __syncthreads();

  const int w = t >> 6, l = t & 63;
  const int quad = l >> 4, lane16 = l & 15;
  const int cw = w * 16 + lane16;           // 0..63
  f32x4 acc[8];
  #pragma unroll
  for (int g2 = 0; g2 < 8; ++g2) acc[g2] = (f32x4){0.f, 0.f, 0.f, 0.f};

  const short8* As = (const short8*)A;
  const short8* Bh = (const short8*)pkhi;
  const short8* Bm = (const short8*)pkmd;
  const short8* Bl = (const short8*)pklo;

  __builtin_amdgcn_s_setprio(1);   // T5
  #pragma unroll
  for (int s = 0; s < NOCT / 4; ++s) {
    int ao = (s * 4 + quad) * S16 + lane16;
    short8 ah = As[ao];
    short8 am = As[LP16 / 8 + ao];
    short8 al = As[2 * (LP16 / 8) + ao];
    int bo = (s * 4 + quad) * 512 + cw;
    #pragma unroll
    for (int g2 = 0; g2 < 8; ++g2) {
      short8 bh = Bh[bo + g2 * 64];
      short8 bm = Bm[bo + g2 * 64];
      short8 bl = Bl[bo + g2 * 64];
      MFMA6(acc[g2], ah, am, al, bh, bm, bl);
    }
  }
  __builtin_amdgcn_s_setprio(0);
  literal_epi16(acc, bsum, bvec, rcnt, hL, Lbuf, rowBase, quad, cw);
}

// ---------------- fp16 4-term step kernels (steps NBF..7) ----------------

__global__ __launch_bounds__(256, 4) void clause_f2(
    const float* __restrict__ Lbuf, const int* __restrict__ csc, const int* __restrict__ ccnt,
    const unsigned short* __restrict__ qkhi, const unsigned short* __restrict__ qklo,
    const float* __restrict__ bsum, const float* __restrict__ bvec,
    float* __restrict__ hC, float* __restrict__ Cs) {
  __shared__ unsigned short A[2 * CP16];    // 17,408 B
  __shared__ int IDX[16 * COLW];            // 4 KB
  const int t = threadIdx.x;
  const int rowBase = blockIdx.x * 16;

  ((int4*)IDX)[t] = ((const int4*)(csc + rowBase * COLW))[t];
  __syncthreads();

  { // gather + stage: 16 threads/row, 8 floats each; K = [msgs | hC]
    const int r = t >> 4, sub = t & 15;
    const int c = rowBase + r;
    int cnt = ccnt[c]; if (cnt > COLW) cnt = COLW;
    const int* lst = IDX + r * COLW;
    float4 a0 = make_float4(0, 0, 0, 0), a1 = a0;
    int j = 0;
    for (; j + 8 <= cnt; j += 8) {
      float4 p0[8], p1[8];
      #pragma unroll
      for (int u = 0; u < 8; ++u) {
        const float4* s4 = (const float4*)(Lbuf + (size_t)lst[j + u] * DD) + sub * 2;
        p0[u] = s4[0]; p1[u] = s4[1];
      }
      #pragma unroll
      for (int u = 0; u < 8; ++u) { add4(a0, p0[u]); add4(a1, p1[u]); }
    }
    for (; j < cnt; ++j) {
      const float4* s4 = (const float4*)(Lbuf + (size_t)lst[j] * DD) + sub * 2;
      add4(a0, s4[0]); add4(a1, s4[1]);
    }
    store_oct2g(A, S16, CP16, sub, r, a0, a1);
    const float4* h4 = (const float4*)(hC + (size_t)c * DD) + sub * 2;
    store_oct2g(A, S16, CP16, 16 + sub, r, h4[0], h4[1]);
  }
  __syncthreads();

  const int w = t >> 6, l = t & 63;
  const int quad = l >> 4, lane16 = l & 15;
  const int cw = w * 16 + lane16;
  f32x4 acc[8];
  #pragma unroll
  for (int g2 = 0; g2 < 8; ++g2) acc[g2] = (f32x4){0.f, 0.f, 0.f, 0.f};

  const half8* As = (const half8*)A;
  const half8* Bh = (const half8*)qkhi;
  const half8* Bl = (const half8*)qklo;

  __builtin_amdgcn_s_setprio(1);   // T5
  #pragma unroll
  for (int s = 0; s < 8; ++s) {
    int ao = (s * 4 + quad) * S16 + lane16;
    half8 ah = As[ao];
    half8 al = As[CP16 / 8 + ao];
    int bo = (s * 4 + quad) * 512 + cw;
    #pragma unroll
    for (int g2 = 0; g2 < 8; ++g2) {
      half8 bh = Bh[bo + g2 * 64];
      half8 bl = Bl[bo + g2 * 64];
      MFMA4(acc[g2], ah, al, bh, bl);
    }
  }
  __builtin_amdgcn_s_setprio(0);
  clause_epi16(acc, bsum, bvec, ccnt, hC, Cs, rowBase, quad, cw);
}

__global__ __launch_bounds__(256, 4) void literal_f2(
    const float* __restrict__ Cs, const int* __restrict__ csr, const int* __restrict__ rcnt,
    const unsigned short* __restrict__ qkhi, const unsigned short* __restrict__ qklo,
    const float* __restrict__ bsum, const float* __restrict__ bvec,
    float* __restrict__ hL, float* __restrict__ Lbuf) {
  __shared__ unsigned short A[2 * LP16];    // 26,112 B
  __shared__ int IDX[16 * ROWW];            // 6 KB
  const int t = threadIdx.x;
  const int rowBase = blockIdx.x * 16;

  // 16 rows x 96 ints = 384 int4
  ((int4*)IDX)[t] = ((const int4*)(csr + rowBase * ROWW))[t];
  if (t < 128) ((int4*)IDX)[t + 256] = ((const int4*)(csr + rowBase * ROWW))[t + 256];
  __syncthreads();

  { // gather + stage: 16 threads/row, 8 floats each; K = [msgs | L | hL]
    const int r = t >> 4, sub = t & 15;
    const int lr = rowBase + r;
    int cnt = rcnt[lr]; if (cnt > ROWW) cnt = ROWW;
    const int* lst = IDX + r * ROWW;
    float4 a0 = make_float4(0, 0, 0, 0), a1 = a0;
    int j = 0;
    for (; j + 8 <= cnt; j += 8) {
      float4 p0[8], p1[8];
      #pragma unroll
      for (int u = 0; u < 8; ++u) {
        const float4* s4 = (const float4*)(Cs + (size_t)lst[j + u] * DD) + sub * 2;
        p0[u] = s4[0]; p1[u] = s4[1];
      }
      #pragma unroll
      for (int u = 0; u < 8; ++u) { add4(a0, p0[u]); add4(a1, p1[u]); }
    }
    for (; j < cnt; ++j) {
      const float4* s4 = (const float4*)(Cs + (size_t)lst[j] * DD) + sub * 2;
      add4(a0, s4[0]); add4(a1, s4[1]);
    }
    store_oct2g(A, S16, LP16, sub, r, a0, a1);
    const float4* l4 = (const float4*)(Lbuf + (size_t)lr * DD) + sub * 2;
    store_oct2g(A, S16, LP16, 16 + sub, r, l4[0], l4[1]);
    const float4* h4 = (const float4*)(hL + (size_t)lr * DD) + sub * 2;
    store_oct2g(A, S16, LP16, 32 + sub, r, h4[0], h4[1]);
  }
  __syncthreads();

  const int w = t >> 6, l = t & 63;
  const int quad = l >> 4, lane16 = l & 15;
  const int cw = w * 16 + lane16;
  f32x4 acc[8];
  #pragma unroll
  for (int g2 = 0; g2 < 8; ++g2) acc[g2] = (f32x4){0.f, 0.f, 0.f, 0.f};

  const half8* As = (const half8*)A;
  const half8* Bh = (const half8*)qkhi;
  const half8* Bl = (const half8*)qklo;

  __builtin_amdgcn_s_setprio(1);   // T5
  #pragma unroll
  for (int s = 0; s < 12; ++s) {            // K=384
    int ao = (s * 4 + quad) * S16 + lane16;
    half8 ah = As[ao];
    half8 al = As[LP16 / 8 + ao];
    int bo = (s * 4 + quad) * 512 + cw;
    #pragma unroll
    for (int g2 = 0; g2 < 8; ++g2) {
      half8 bh = Bh[bo + g2 * 64];
      half8 bl = Bl[bo + g2 * 64];
      MFMA4(acc[g2], ah, al, bh, bl);
    }
  }
  __builtin_amdgcn_s_setprio(0);
  literal_epi16(acc, bsum, bvec, rcnt, hL, Lbuf, rowBase, quad, cw);
}

// ---------------- launch ----------------

extern "C" void kernel_launch(void* const* d_in, const int* in_sizes, int n_in,
                              void* d_out, int out_size, void* d_ws, size_t ws_size,
                              hipStream_t stream) {
  const float* L0   = (const float*)d_in[0];
  // d_in[1] = C_state (unused), d_in[5] = n_vars (flip is identity)
  const float* hL0  = (const float*)d_in[2];
  const float* hC0  = (const float*)d_in[3];
  const float* M    = (const float*)d_in[4];
  const float* Wlc  = (const float*)d_in[6];
  const float* blc  = (const float*)d_in[7];
  const float* Wcl  = (const float*)d_in[8];
  const float* bcl  = (const float*)d_in[9];
  const float* WihC = (const float*)d_in[10];
  const float* WhhC = (const float*)d_in[11];
  const float* bihC = (const float*)d_in[12];
  const float* bhhC = (const float*)d_in[13];
  const float* WihL = (const float*)d_in[14];
  const float* WhhL = (const float*)d_in[15];
  const float* bihL = (const float*)d_in[16];
  const float* bhhL = (const float*)d_in[17];

  float* ws    = (float*)d_ws;
  float* hL    = ws;                         // NL*DD
  float* hC    = hL + NL * DD;               // NC*DD
  float* Cs    = hC + NC * DD;               // NC*DD
  float* bsumC = Cs + NC * DD;               // 512 each
  float* bvecC = bsumC + 512;
  float* bsumL = bvecC + 512;
  float* bvecL = bsumL + 512;
  unsigned short* pkChi = (unsigned short*)(bvecL + 512);   // bf16 clause: 3 x 256*512
  unsigned short* pkCmd = pkChi + 256 * 512;
  unsigned short* pkClo = pkCmd + 256 * 512;
  unsigned short* pkLhi = pkClo + 256 * 512;                // bf16 literal: 3 x 384*512
  unsigned short* pkLmd = pkLhi + 384 * 512;
  unsigned short* pkLlo = pkLmd + 384 * 512;
  unsigned short* qkChi = pkLlo + 384 * 512;                // fp16 clause: 2 x 256*512
  unsigned short* qkClo = qkChi + 256 * 512;
  unsigned short* qkLhi = qkClo + 256 * 512;                // fp16 literal: 2 x 384*512
  unsigned short* qkLlo = qkLhi + 384 * 512;
  int* csr  = (int*)(qkLlo + 384 * 512);     // NL*ROWW
  int* csc  = csr + NL * ROWW;               // NC*COLW
  int* rcnt = csc + NC * COLW;               // NL
  int* ccnt = rcnt + NL;                     // NC (contiguous with rcnt)
  float* Lbuf = (float*)d_out;               // literal state lives in d_out

  hipMemsetAsync(rcnt, 0, (NL + NC) * sizeof(int), stream);

  init_states<<<1024, 256, 0, stream>>>((float4*)Lbuf, (const float4*)L0,
                                        (float4*)hL, (const float4*)hL0,
                                        (float4*)hC, (const float4*)hC0);

  scan_M<<<4096, 256, 0, stream>>>((const float4*)M, csr, csc, rcnt, ccnt);

  build_packC<<<(256 * 512) / 256, 256, 0, stream>>>(WihC, Wlc, WhhC,
                                                     pkChi, pkCmd, pkClo, qkChi, qkClo);
  build_packL<<<(384 * 512) / 256, 256, 0, stream>>>(WihL, Wcl, WhhL,
                                                     pkLhi, pkLmd, pkLlo, qkLhi, qkLlo);
  build_bias<<<4, 256, 0, stream>>>(bihC, bhhC, WihC, blc, bihL, bhhL, WihL, bcl,
                                    bsumC, bvecC, bsumL, bvecL);

  // step 0: hidden states are zeros -> truncated K (exactly equivalent)
  clause_bf3<16, false><<<NC / 16, 256, 0, stream>>>(Lbuf, csc, ccnt, pkChi, pkCmd, pkClo,
                                                     bsumC, bvecC, hC, Cs);
  literal_bf3<32, false><<<NL / 16, 256, 0, stream>>>(Cs, csr, rcnt, pkLhi, pkLmd, pkLlo,
                                                      bsumL, bvecL, hL, Lbuf);
  // remaining bf16 steps
  for (int t = 1; t < NBF; ++t) {
    clause_bf3<32, true><<<NC / 16, 256, 0, stream>>>(Lbuf, csc, ccnt, pkChi, pkCmd, pkClo,
                                                      bsumC, bvecC, hC, Cs);
    literal_bf3<48, true><<<NL / 16, 256, 0, stream>>>(Cs, csr, rcnt, pkLhi, pkLmd, pkLlo,
                                                       bsumL, bvecL, hL, Lbuf);
  }
  // fp16 steps
  for (int t = NBF; t < TSTEPS; ++t) {
    clause_f2<<<NC / 16, 256, 0, stream>>>(Lbuf, csc, ccnt, qkChi, qkClo,
                                           bsumC, bvecC, hC, Cs);
    literal_f2<<<NL / 16, 256, 0, stream>>>(Cs, csr, rcnt, qkLhi, qkLlo,
                                            bsumL, bvecL, hL, Lbuf);
  }
}

// Round 8
// 1230.530 us; speedup vs baseline: 2.5639x; 1.1592x over previous
//
#include <hip/hip_runtime.h>

#define DD   128
#define NL   8000
#define NC   16000
#define TSTEPS 8
#define NBF  2     // steps 0..1 bf16 6-term; steps 2..7 fp16 3-term
#define ROWW 96    // max clauses per literal (mean 40, std 6.3)
#define COLW 64    // max literals per clause (mean 20, std 4.4)

// clause kernels: 32-row tiles, K=256 -> 32 octs, stride 33 short8 (pad)
#define OS   33
#define SPLITS8 (32 * OS)        // oct-slots per plane = 1056
#define SPLIT   (SPLITS8 * 8)    // shorts per plane = 8448
// literal bf16 kernel: 16-row tiles, K=384 -> 48 octs, stride 17 short8
#define LSTR 17
#define LSPL (48 * LSTR * 8)     // shorts per plane = 6528
// literal fp16 kernel: 32-row tiles, K=384 -> 48 octs, stride 33 short8
#define L2S  33
#define L2SPL (48 * L2S * 8)     // shorts per plane = 12672

typedef __attribute__((ext_vector_type(8))) short  short8;
typedef __attribute__((ext_vector_type(8))) _Float16 half8;
typedef __attribute__((ext_vector_type(4))) float  f32x4;

__device__ __forceinline__ float frcp(float x) { return __builtin_amdgcn_rcpf(x); }
__device__ __forceinline__ float sigm(float x) { return frcp(1.f + __expf(-x)); }
__device__ __forceinline__ float tanh_(float x) {
  float e = __expf(2.f * x);
  return 1.f - 2.f * frcp(e + 1.f);
}
__device__ __forceinline__ void add4(float4& a, const float4 b) {
  a.x += b.x; a.y += b.y; a.z += b.z; a.w += b.w;
}
__device__ __forceinline__ unsigned short bfround(float v) {  // RNE fp32 -> bf16
  unsigned u = __float_as_uint(v);
  return (unsigned short)((u + 0x7FFF + ((u >> 16) & 1)) >> 16);
}
__device__ __forceinline__ float bf2f(unsigned short b) {
  return __uint_as_float(((unsigned)b) << 16);
}
__device__ __forceinline__ void splitf16(float v, unsigned short& h, unsigned short& l) {
  _Float16 hh = (_Float16)v;           // RNE
  float r = v - (float)hh;             // exact
  _Float16 ll = (_Float16)r;
  h = __builtin_bit_cast(unsigned short, hh);
  l = __builtin_bit_cast(unsigned short, ll);
}
__device__ __forceinline__ int4 packi4(const unsigned short* p) {
  return make_int4(p[0] | ((int)p[1] << 16), p[2] | ((int)p[3] << 16),
                   p[4] | ((int)p[5] << 16), p[6] | ((int)p[7] << 16));
}

// bf16 triple-split 8 floats -> 3 octets, clause layout (stride OS, plane SPLIT)
__device__ __forceinline__ void store_oct3(unsigned short* A, int oct, int m,
                                           float4 a, float4 b) {
  float f[8] = {a.x, a.y, a.z, a.w, b.x, b.y, b.z, b.w};
  unsigned short h[8], md[8], lo[8];
  #pragma unroll
  for (int j = 0; j < 8; ++j) {
    h[j] = bfround(f[j]);
    float r1 = f[j] - bf2f(h[j]);       // exact (Sterbenz)
    md[j] = bfround(r1);
    float r2 = r1 - bf2f(md[j]);        // exact
    lo[j] = bfround(r2);
  }
  int base = (oct * OS + m) * 8;
  *(int4*)(A + base)             = packi4(h);
  *(int4*)(A + SPLIT + base)     = packi4(md);
  *(int4*)(A + 2 * SPLIT + base) = packi4(lo);
}

// fp16 2-split 8 floats -> 2 octets, generic layout (strideS8 slots, plane in shorts)
__device__ __forceinline__ void store_oct2g(unsigned short* A, int strideS8, int plane,
                                            int oct, int m, float4 a, float4 b) {
  float f[8] = {a.x, a.y, a.z, a.w, b.x, b.y, b.z, b.w};
  unsigned short h[8], lo[8];
  #pragma unroll
  for (int j = 0; j < 8; ++j) splitf16(f[j], h[j], lo[j]);
  int base = (oct * strideS8 + m) * 8;
  *(int4*)(A + base)         = packi4(h);
  *(int4*)(A + plane + base) = packi4(lo);
}

// bf16 triple-split 4 floats -> half-octet, 16-row literal layout
__device__ __forceinline__ void store_half3L(unsigned short* A, int oct, int half, int m,
                                             float4 a) {
  float f[4] = {a.x, a.y, a.z, a.w};
  unsigned short h[4], md[4], lo[4];
  #pragma unroll
  for (int j = 0; j < 4; ++j) {
    h[j] = bfround(f[j]);
    float r1 = f[j] - bf2f(h[j]);
    md[j] = bfround(r1);
    float r2 = r1 - bf2f(md[j]);
    lo[j] = bfround(r2);
  }
  int base = (oct * LSTR + m) * 8 + half * 4;
  *(int2*)(A + base)            = make_int2(h[0]  | ((int)h[1]  << 16), h[2]  | ((int)h[3]  << 16));
  *(int2*)(A + LSPL + base)     = make_int2(md[0] | ((int)md[1] << 16), md[2] | ((int)md[3] << 16));
  *(int2*)(A + 2 * LSPL + base) = make_int2(lo[0] | ((int)lo[1] << 16), lo[2] | ((int)lo[3] << 16));
}

__device__ __forceinline__ void split_store_bf3(float w, int idx, unsigned short* hi,
                                                unsigned short* md, unsigned short* lo) {
  unsigned short h = bfround(w);
  float r1 = w - bf2f(h);
  unsigned short m = bfround(r1);
  float r2 = r1 - bf2f(m);
  hi[idx] = h; md[idx] = m; lo[idx] = bfround(r2);
}

// 6-term bf16 triple-split product (error ~2^-27)
#define MFMA6(ACC, AH, AM, AL, BH, BM, BL)                                   \
  ACC = __builtin_amdgcn_mfma_f32_16x16x32_bf16(AH, BH, ACC, 0, 0, 0);       \
  ACC = __builtin_amdgcn_mfma_f32_16x16x32_bf16(AH, BM, ACC, 0, 0, 0);       \
  ACC = __builtin_amdgcn_mfma_f32_16x16x32_bf16(AM, BH, ACC, 0, 0, 0);       \
  ACC = __builtin_amdgcn_mfma_f32_16x16x32_bf16(AH, BL, ACC, 0, 0, 0);       \
  ACC = __builtin_amdgcn_mfma_f32_16x16x32_bf16(AL, BH, ACC, 0, 0, 0);       \
  ACC = __builtin_amdgcn_mfma_f32_16x16x32_bf16(AM, BM, ACC, 0, 0, 0);

// 3-term fp16 2-split product. The dropped AL*BL term is <= 2^-22*|A||B| --
// the same order as the fp16-split representation residual, so total error
// merely ~doubles at the 2^-22 scale (invisible vs the ~0.012 absmax).
// Saves 25% of fp16 MFMA issue.
#define MFMA3(ACC, AH, AL, BH, BL)                                           \
  ACC = __builtin_amdgcn_mfma_f32_16x16x32_f16(AH, BH, ACC, 0, 0, 0);        \
  ACC = __builtin_amdgcn_mfma_f32_16x16x32_f16(AH, BL, ACC, 0, 0, 0);        \
  ACC = __builtin_amdgcn_mfma_f32_16x16x32_f16(AL, BH, ACC, 0, 0, 0);

// ---------------- fused preprocessing ----------------
// R7: init_states and scan_M write disjoint buffers -> one kernel, one less
// dispatch boundary. (rcnt/ccnt zeroing must stay a separate prior dispatch:
// scan's atomics race with zeroing inside one kernel.)
__global__ __launch_bounds__(256) void prep_graph(
    float4* __restrict__ Lbuf, const float4* __restrict__ L0,
    float4* __restrict__ hL, const float4* __restrict__ hL0,
    float4* __restrict__ hC, const float4* __restrict__ hC0,
    const float4* __restrict__ M4,
    int* __restrict__ csr, int* __restrict__ csc,
    int* __restrict__ rcnt, int* __restrict__ ccnt) {
  int i = blockIdx.x * 256 + threadIdx.x, stride = gridDim.x * 256;
  for (int j = i; j < NL * DD / 4; j += stride) { Lbuf[j] = L0[j]; hL[j] = hL0[j]; }
  for (int j = i; j < NC * DD / 4; j += stride) hC[j] = hC0[j];

  // one pass over M (512 MB): padded-ELL both directions
  const int total = (NL * NC) / 4;
  for (int idx = i; idx < total; idx += stride) {
    float4 v = M4[idx];
    if (v.x == 0.f && v.y == 0.f && v.z == 0.f && v.w == 0.f) continue;
    int base = idx * 4;
    int l = base / NC;
    int c0 = base - l * NC;
    float vv[4] = {v.x, v.y, v.z, v.w};
    #pragma unroll
    for (int e = 0; e < 4; ++e) {
      if (vv[e] != 0.f) {
        int c = c0 + e;
        int rp = atomicAdd(&rcnt[l], 1);
        if (rp < ROWW) csr[l * ROWW + rp] = c;
        int cp = atomicAdd(&ccnt[c], 1);
        if (cp < COLW) csc[c * COLW + cp] = l;
      }
    }
  }
}

// R7: build_packC (512 blocks) + build_packL (768 blocks) + build_bias (4
// blocks) are fully independent -> one 1284-block kernel (block-granular
// branch, no divergence inside blocks). Two fewer dispatch boundaries.
__global__ __launch_bounds__(256) void build_all(
    const float* __restrict__ WihC, const float* __restrict__ Wlc,
    const float* __restrict__ WhhC, const float* __restrict__ blc,
    const float* __restrict__ bihC, const float* __restrict__ bhhC,
    const float* __restrict__ WihL, const float* __restrict__ Wcl,
    const float* __restrict__ WhhL, const float* __restrict__ bcl,
    const float* __restrict__ bihL, const float* __restrict__ bhhL,
    unsigned short* __restrict__ pkChi, unsigned short* __restrict__ pkCmd,
    unsigned short* __restrict__ pkClo,
    unsigned short* __restrict__ qkChi, unsigned short* __restrict__ qkClo,
    unsigned short* __restrict__ pkLhi, unsigned short* __restrict__ pkLmd,
    unsigned short* __restrict__ pkLlo,
    unsigned short* __restrict__ qkLhi, unsigned short* __restrict__ qkLlo,
    float* __restrict__ bsumC, float* __restrict__ bvecC,
    float* __restrict__ bsumL, float* __restrict__ bvecL) {
  const int b = blockIdx.x, t = threadIdx.x;
  if (b < 512) {            // clause pack: B[k][n]
    int i = b * 256 + t;
    int k = i >> 9, n = i & 511;
    float w;
    if (k < 128) {
      float s = 0.f;
      for (int d = 0; d < 128; ++d) s += WihC[n * 128 + d] * Wlc[d * 128 + k];
      w = s;
    } else {
      w = WhhC[n * 128 + (k - 128)];
    }
    int idx = ((k >> 3) * 512 + n) * 8 + (k & 7);
    split_store_bf3(w, idx, pkChi, pkCmd, pkClo);
    splitf16(w, qkChi[idx], qkClo[idx]);
  } else if (b < 1280) {    // literal pack
    int i = (b - 512) * 256 + t;
    int k = i >> 9, n = i & 511;
    float w;
    if (k < 128) {
      float s = 0.f;
      for (int d = 0; d < 128; ++d) s += WihL[n * 256 + d] * Wcl[d * 128 + k];
      w = s;
    } else if (k < 256) {
      w = WihL[n * 256 + k];
    } else {
      w = WhhL[n * 128 + (k - 256)];
    }
    int idx = ((k >> 3) * 512 + n) * 8 + (k & 7);
    split_store_bf3(w, idx, pkLhi, pkLmd, pkLlo);
    splitf16(w, qkLhi[idx], qkLlo[idx]);
  } else {                  // biases: blocks 1280..1283, i in [0,1024)
    int i = (b - 1280) * 256 + t;
    if (i < 512) {
      bsumC[i] = bihC[i] + bhhC[i];
      float s = 0.f;
      for (int d = 0; d < 128; ++d) s += WihC[i * 128 + d] * blc[d];
      bvecC[i] = s;
    } else if (i < 1024) {
      int n = i - 512;
      bsumL[n] = bihL[n] + bhhL[n];
      float s = 0.f;
      for (int d = 0; d < 128; ++d) s += WihL[n * 256 + d] * bcl[d];
      bvecL[n] = s;
    }
  }
}

// ---------------- shared epilogues ----------------
__device__ __forceinline__ void clause_epilogue(
    const f32x4 acc[2][4], const float* bsum, const float* bvec, const int* ccnt,
    float* hC, float* Cs, int rowBase, int quad, int cw) {
  float bs_[4], bv_[4];
  #pragma unroll
  for (int g = 0; g < 4; ++g) { bs_[g] = bsum[g * 128 + cw]; bv_[g] = bvec[g * 128 + cw]; }
  #pragma unroll
  for (int mt = 0; mt < 2; ++mt) {
    #pragma unroll
    for (int reg = 0; reg < 4; ++reg) {
      int row = rowBase + mt * 16 + quad * 4 + reg;
      float deg = (float)ccnt[row];
      float co = hC[(size_t)row * DD + cw];
      float iv = acc[mt][0][reg] + bs_[0] + deg * bv_[0];
      float fv = acc[mt][1][reg] + bs_[1] + deg * bv_[1];
      float gv = acc[mt][2][reg] + bs_[2] + deg * bv_[2];
      float ov = acc[mt][3][reg] + bs_[3] + deg * bv_[3];
      float cn = sigm(fv) * co + sigm(iv) * tanh_(gv);
      hC[(size_t)row * DD + cw] = cn;
      Cs[(size_t)row * DD + cw] = sigm(ov) * tanh_(cn);
    }
  }
}

__device__ __forceinline__ void literal_epilogue2(
    const f32x4 acc[2][4], const float* bsum, const float* bvec, const int* rcnt,
    float* hL, float* Lbuf, int rowBase, int quad, int cw) {
  float bs_[4], bv_[4];
  #pragma unroll
  for (int g = 0; g < 4; ++g) { bs_[g] = bsum[g * 128 + cw]; bv_[g] = bvec[g * 128 + cw]; }
  #pragma unroll
  for (int mt = 0; mt < 2; ++mt) {
    #pragma unroll
    for (int reg = 0; reg < 4; ++reg) {
      int row = rowBase + mt * 16 + quad * 4 + reg;
      float deg = (float)rcnt[row];
      float co = hL[(size_t)row * DD + cw];
      float iv = acc[mt][0][reg] + bs_[0] + deg * bv_[0];
      float fv = acc[mt][1][reg] + bs_[1] + deg * bv_[1];
      float gv = acc[mt][2][reg] + bs_[2] + deg * bv_[2];
      float ov = acc[mt][3][reg] + bs_[3] + deg * bv_[3];
      float cn = sigm(fv) * co + sigm(iv) * tanh_(gv);
      hL[(size_t)row * DD + cw] = cn;
      Lbuf[(size_t)row * DD + cw] = sigm(ov) * tanh_(cn);
    }
  }
}

// ---------------- bf16 6-term step kernels (steps 0..NBF-1) ----------------
// Proven R2 structure (1270 us best): 512 threads, (512,2), setprio.

template <int NOCT, bool STAGE_H>
__global__ __launch_bounds__(512, 2) void clause_bf3(
    const float* __restrict__ Lbuf, const int* __restrict__ csc, const int* __restrict__ ccnt,
    const unsigned short* __restrict__ pkhi, const unsigned short* __restrict__ pkmd,
    const unsigned short* __restrict__ pklo,
    const float* __restrict__ bsum, const float* __restrict__ bvec,
    float* __restrict__ hC, float* __restrict__ Cs) {
  __shared__ unsigned short A[3 * SPLIT];   // 50,688 B
  __shared__ int IDX[32 * COLW];            // 8 KB
  const int t = threadIdx.x;
  const int rowBase = blockIdx.x * 32;

  ((int4*)IDX)[t] = ((const int4*)(csc + rowBase * COLW))[t];
  __syncthreads();

  { // gather + stage: 16 threads/row, 8 floats each; K = [msgs | hC?]
    const int r = t >> 4, sub = t & 15;
    const int c = rowBase + r;
    int cnt = ccnt[c]; if (cnt > COLW) cnt = COLW;
    const int* lst = IDX + r * COLW;
    float4 a0 = make_float4(0, 0, 0, 0), a1 = a0;
    int j = 0;
    for (; j + 8 <= cnt; j += 8) {
      float4 p0[8], p1[8];
      #pragma unroll
      for (int u = 0; u < 8; ++u) {
        const float4* s4 = (const float4*)(Lbuf + (size_t)lst[j + u] * DD) + sub * 2;
        p0[u] = s4[0]; p1[u] = s4[1];
      }
      #pragma unroll
      for (int u = 0; u < 8; ++u) { add4(a0, p0[u]); add4(a1, p1[u]); }
    }
    for (; j < cnt; ++j) {
      const float4* s4 = (const float4*)(Lbuf + (size_t)lst[j] * DD) + sub * 2;
      add4(a0, s4[0]); add4(a1, s4[1]);
    }
    store_oct3(A, sub, r, a0, a1);
    if constexpr (STAGE_H) {
      const float4* h4 = (const float4*)(hC + (size_t)c * DD) + sub * 2;
      store_oct3(A, 16 + sub, r, h4[0], h4[1]);
    }
  }
  __syncthreads();

  const int w = t >> 6, l = t & 63;
  const int quad = l >> 4, lane16 = l & 15;
  const int cw = w * 16 + lane16;
  f32x4 acc[2][4];
  #pragma unroll
  for (int mt = 0; mt < 2; ++mt)
    #pragma unroll
    for (int g = 0; g < 4; ++g) acc[mt][g] = (f32x4){0.f, 0.f, 0.f, 0.f};

  const short8* As = (const short8*)A;
  const short8* Bh = (const short8*)pkhi;
  const short8* Bm = (const short8*)pkmd;
  const short8* Bl = (const short8*)pklo;

  __builtin_amdgcn_s_setprio(1);   // T5 (R2: +1.2%)
  #pragma unroll
  for (int s = 0; s < NOCT / 4; ++s) {
    int ao = (s * 4 + quad) * OS + lane16;
    short8 a0h = As[ao],                a1h = As[ao + 16];
    short8 a0m = As[SPLITS8 + ao],      a1m = As[SPLITS8 + ao + 16];
    short8 a0l = As[2 * SPLITS8 + ao],  a1l = As[2 * SPLITS8 + ao + 16];
    int bo = (s * 4 + quad) * 512 + cw;
    #pragma unroll
    for (int g = 0; g < 4; ++g) {
      short8 bh = Bh[bo + g * 128];
      short8 bm = Bm[bo + g * 128];
      short8 bl = Bl[bo + g * 128];
      MFMA6(acc[0][g], a0h, a0m, a0l, bh, bm, bl);
      MFMA6(acc[1][g], a1h, a1m, a1l, bh, bm, bl);
    }
  }
  __builtin_amdgcn_s_setprio(0);
  clause_epilogue(acc, bsum, bvec, ccnt, hC, Cs, rowBase, quad, cw);
}

template <int NOCT, bool STAGE_H>
__global__ __launch_bounds__(512, 2) void literal_bf3(
    const float* __restrict__ Cs, const int* __restrict__ csr, const int* __restrict__ rcnt,
    const unsigned short* __restrict__ pkhi, const unsigned short* __restrict__ pkmd,
    const unsigned short* __restrict__ pklo,
    const float* __restrict__ bsum, const float* __restrict__ bvec,
    float* __restrict__ hL, float* __restrict__ Lbuf) {
  __shared__ unsigned short A[3 * LSPL];    // 39,168 B
  __shared__ int IDX[16 * ROWW];            // 6 KB
  const int t = threadIdx.x;
  const int rowBase = blockIdx.x * 16;

  if (t < 384) ((int4*)IDX)[t] = ((const int4*)(csr + rowBase * ROWW))[t];
  __syncthreads();

  { // gather + stage: 32 threads/row, 4 floats each; K = [msgs | L | hL?]
    const int r = t >> 5, cg2 = t & 31;
    const int lr = rowBase + r;
    int cnt = rcnt[lr]; if (cnt > ROWW) cnt = ROWW;
    const int* lst = IDX + r * ROWW;
    float4 a0 = make_float4(0, 0, 0, 0);
    int j = 0;
    for (; j + 8 <= cnt; j += 8) {
      float4 p[8];
      #pragma unroll
      for (int u = 0; u < 8; ++u)
        p[u] = ((const float4*)(Cs + (size_t)lst[j + u] * DD))[cg2];
      #pragma unroll
      for (int u = 0; u < 8; ++u) add4(a0, p[u]);
    }
    for (; j < cnt; ++j)
      add4(a0, ((const float4*)(Cs + (size_t)lst[j] * DD))[cg2]);
    store_half3L(A, cg2 >> 1, cg2 & 1, r, a0);
    store_half3L(A, 16 + (cg2 >> 1), cg2 & 1, r,
                 ((const float4*)(Lbuf + (size_t)lr * DD))[cg2]);
    if constexpr (STAGE_H)
      store_half3L(A, 32 + (cg2 >> 1), cg2 & 1, r,
                   ((const float4*)(hL + (size_t)lr * DD))[cg2]);
  }
  __syncthreads();

  const int w = t >> 6, l = t & 63;
  const int quad = l >> 4, lane16 = l & 15;
  const int cw = w * 16 + lane16;
  f32x4 acc[4];
  #pragma unroll
  for (int g = 0; g < 4; ++g) acc[g] = (f32x4){0.f, 0.f, 0.f, 0.f};

  const short8* As = (const short8*)A;
  const short8* Bh = (const short8*)pkhi;
  const short8* Bm = (const short8*)pkmd;
  const short8* Bl = (const short8*)pklo;

  __builtin_amdgcn_s_setprio(1);   // T5
  #pragma unroll
  for (int s = 0; s < NOCT / 4; ++s) {
    int ao = (s * 4 + quad) * LSTR + lane16;
    short8 ah = As[ao];
    short8 am = As[LSPL / 8 + ao];
    short8 al = As[2 * (LSPL / 8) + ao];
    int bo = (s * 4 + quad) * 512 + cw;
    #pragma unroll
    for (int g = 0; g < 4; ++g) {
      short8 bh = Bh[bo + g * 128];
      short8 bm = Bm[bo + g * 128];
      short8 bl = Bl[bo + g * 128];
      MFMA6(acc[g], ah, am, al, bh, bm, bl);
    }
  }
  __builtin_amdgcn_s_setprio(0);

  float bs_[4], bv_[4];
  #pragma unroll
  for (int g = 0; g < 4; ++g) { bs_[g] = bsum[g * 128 + cw]; bv_[g] = bvec[g * 128 + cw]; }
  #pragma unroll
  for (int reg = 0; reg < 4; ++reg) {
    int row = rowBase + quad * 4 + reg;
    float deg = (float)rcnt[row];
    float co = hL[(size_t)row * DD + cw];
    float iv = acc[0][reg] + bs_[0] + deg * bv_[0];
    float fv = acc[1][reg] + bs_[1] + deg * bv_[1];
    float gv = acc[2][reg] + bs_[2] + deg * bv_[2];
    float ov = acc[3][reg] + bs_[3] + deg * bv_[3];
    float cn = sigm(fv) * co + sigm(iv) * tanh_(gv);
    hL[(size_t)row * DD + cw] = cn;
    Lbuf[(size_t)row * DD + cw] = sigm(ov) * tanh_(cn);
  }
}

// ---------------- fp16 3-term step kernels (steps NBF..7) ----------------

__global__ __launch_bounds__(512, 2) void clause_f2(
    const float* __restrict__ Lbuf, const int* __restrict__ csc, const int* __restrict__ ccnt,
    const unsigned short* __restrict__ qkhi, const unsigned short* __restrict__ qklo,
    const float* __restrict__ bsum, const float* __restrict__ bvec,
    float* __restrict__ hC, float* __restrict__ Cs) {
  __shared__ unsigned short A[2 * SPLIT];   // 33,792 B
  __shared__ int IDX[32 * COLW];            // 8 KB
  const int t = threadIdx.x;
  const int rowBase = blockIdx.x * 32;

  ((int4*)IDX)[t] = ((const int4*)(csc + rowBase * COLW))[t];
  __syncthreads();

  {
    const int r = t >> 4, sub = t & 15;
    const int c = rowBase + r;
    int cnt = ccnt[c]; if (cnt > COLW) cnt = COLW;
    const int* lst = IDX + r * COLW;
    float4 a0 = make_float4(0, 0, 0, 0), a1 = a0;
    int j = 0;
    for (; j + 8 <= cnt; j += 8) {
      float4 p0[8], p1[8];
      #pragma unroll
      for (int u = 0; u < 8; ++u) {
        const float4* s4 = (const float4*)(Lbuf + (size_t)lst[j + u] * DD) + sub * 2;
        p0[u] = s4[0]; p1[u] = s4[1];
      }
      #pragma unroll
      for (int u = 0; u < 8; ++u) { add4(a0, p0[u]); add4(a1, p1[u]); }
    }
    for (; j < cnt; ++j) {
      const float4* s4 = (const float4*)(Lbuf + (size_t)lst[j] * DD) + sub * 2;
      add4(a0, s4[0]); add4(a1, s4[1]);
    }
    store_oct2g(A, OS, SPLIT, sub, r, a0, a1);
    const float4* h4 = (const float4*)(hC + (size_t)c * DD) + sub * 2;
    store_oct2g(A, OS, SPLIT, 16 + sub, r, h4[0], h4[1]);
  }
  __syncthreads();

  const int w = t >> 6, l = t & 63;
  const int quad = l >> 4, lane16 = l & 15;
  const int cw = w * 16 + lane16;
  f32x4 acc[2][4];
  #pragma unroll
  for (int mt = 0; mt < 2; ++mt)
    #pragma unroll
    for (int g = 0; g < 4; ++g) acc[mt][g] = (f32x4){0.f, 0.f, 0.f, 0.f};

  const half8* As = (const half8*)A;
  const half8* Bh = (const half8*)qkhi;
  const half8* Bl = (const half8*)qklo;

  __builtin_amdgcn_s_setprio(1);   // T5
  #pragma unroll
  for (int s = 0; s < 8; ++s) {
    int ao = (s * 4 + quad) * OS + lane16;
    half8 a0h = As[ao],           a1h = As[ao + 16];
    half8 a0l = As[SPLITS8 + ao], a1l = As[SPLITS8 + ao + 16];
    int bo = (s * 4 + quad) * 512 + cw;
    #pragma unroll
    for (int g = 0; g < 4; ++g) {
      half8 bh = Bh[bo + g * 128];
      half8 bl = Bl[bo + g * 128];
      MFMA3(acc[0][g], a0h, a0l, bh, bl);
      MFMA3(acc[1][g], a1h, a1l, bh, bl);
    }
  }
  __builtin_amdgcn_s_setprio(0);
  clause_epilogue(acc, bsum, bvec, ccnt, hC, Cs, rowBase, quad, cw);
}

__global__ __launch_bounds__(512, 2) void literal_f2(
    const float* __restrict__ Cs, const int* __restrict__ csr, const int* __restrict__ rcnt,
    const unsigned short* __restrict__ qkhi, const unsigned short* __restrict__ qklo,
    const float* __restrict__ bsum, const float* __restrict__ bvec,
    float* __restrict__ hL, float* __restrict__ Lbuf) {
  __shared__ unsigned short A[2 * L2SPL];   // 50,688 B
  __shared__ int IDX[32 * ROWW];            // 12 KB
  const int t = threadIdx.x;
  const int rowBase = blockIdx.x * 32;

  // stage index lists: 32 rows x 96 ints = 768 int4
  ((int4*)IDX)[t] = ((const int4*)(csr + rowBase * ROWW))[t];
  if (t < 256) ((int4*)IDX)[t + 512] = ((const int4*)(csr + rowBase * ROWW))[t + 512];
  __syncthreads();

  { // gather + stage: 16 threads/row, 8 floats each; K = [msgs | L | hL]
    const int r = t >> 4, sub = t & 15;
    const int lr = rowBase + r;
    int cnt = rcnt[lr]; if (cnt > ROWW) cnt = ROWW;
    const int* lst = IDX + r * ROWW;
    float4 a0 = make_float4(0, 0, 0, 0), a1 = a0;
    int j = 0;
    for (; j + 8 <= cnt; j += 8) {
      float4 p0[8], p1[8];
      #pragma unroll
      for (int u = 0; u < 8; ++u) {
        const float4* s4 = (const float4*)(Cs + (size_t)lst[j + u] * DD) + sub * 2;
        p0[u] = s4[0]; p1[u] = s4[1];
      }
      #pragma unroll
      for (int u = 0; u < 8; ++u) { add4(a0, p0[u]); add4(a1, p1[u]); }
    }
    for (; j < cnt; ++j) {
      const float4* s4 = (const float4*)(Cs + (size_t)lst[j] * DD) + sub * 2;
      add4(a0, s4[0]); add4(a1, s4[1]);
    }
    store_oct2g(A, L2S, L2SPL, sub, r, a0, a1);
    const float4* l4 = (const float4*)(Lbuf + (size_t)lr * DD) + sub * 2;
    store_oct2g(A, L2S, L2SPL, 16 + sub, r, l4[0], l4[1]);
    const float4* h4 = (const float4*)(hL + (size_t)lr * DD) + sub * 2;
    store_oct2g(A, L2S, L2SPL, 32 + sub, r, h4[0], h4[1]);
  }
  __syncthreads();

  const int w = t >> 6, l = t & 63;
  const int quad = l >> 4, lane16 = l & 15;
  const int cw = w * 16 + lane16;
  f32x4 acc[2][4];
  #pragma unroll
  for (int mt = 0; mt < 2; ++mt)
    #pragma unroll
    for (int g = 0; g < 4; ++g) acc[mt][g] = (f32x4){0.f, 0.f, 0.f, 0.f};

  const half8* As = (const half8*)A;        // idx = oct*L2S + m
  const half8* Bh = (const half8*)qkhi;
  const half8* Bl = (const half8*)qklo;

  __builtin_amdgcn_s_setprio(1);   // T5
  #pragma unroll
  for (int s = 0; s < 12; ++s) {            // K=384
    int ao = (s * 4 + quad) * L2S + lane16;
    half8 a0h = As[ao],             a1h = As[ao + 16];
    half8 a0l = As[L2SPL / 8 + ao], a1l = As[L2SPL / 8 + ao + 16];
    int bo = (s * 4 + quad) * 512 + cw;
    #pragma unroll
    for (int g = 0; g < 4; ++g) {
      half8 bh = Bh[bo + g * 128];
      half8 bl = Bl[bo + g * 128];
      MFMA3(acc[0][g], a0h, a0l, bh, bl);
      MFMA3(acc[1][g], a1h, a1l, bh, bl);
    }
  }
  __builtin_amdgcn_s_setprio(0);
  literal_epilogue2(acc, bsum, bvec, rcnt, hL, Lbuf, rowBase, quad, cw);
}

// ---------------- launch ----------------

extern "C" void kernel_launch(void* const* d_in, const int* in_sizes, int n_in,
                              void* d_out, int out_size, void* d_ws, size_t ws_size,
                              hipStream_t stream) {
  const float* L0   = (const float*)d_in[0];
  // d_in[1] = C_state (unused), d_in[5] = n_vars (flip is identity)
  const float* hL0  = (const float*)d_in[2];
  const float* hC0  = (const float*)d_in[3];
  const float* M    = (const float*)d_in[4];
  const float* Wlc  = (const float*)d_in[6];
  const float* blc  = (const float*)d_in[7];
  const float* Wcl  = (const float*)d_in[8];
  const float* bcl  = (const float*)d_in[9];
  const float* WihC = (const float*)d_in[10];
  const float* WhhC = (const float*)d_in[11];
  const float* bihC = (const float*)d_in[12];
  const float* bhhC = (const float*)d_in[13];
  const float* WihL = (const float*)d_in[14];
  const float* WhhL = (const float*)d_in[15];
  const float* bihL = (const float*)d_in[16];
  const float* bhhL = (const float*)d_in[17];

  float* ws    = (float*)d_ws;
  float* hL    = ws;                         // NL*DD
  float* hC    = hL + NL * DD;               // NC*DD
  float* Cs    = hC + NC * DD;               // NC*DD
  float* bsumC = Cs + NC * DD;               // 512 each
  float* bvecC = bsumC + 512;
  float* bsumL = bvecC + 512;
  float* bvecL = bsumL + 512;
  unsigned short* pkChi = (unsigned short*)(bvecL + 512);   // bf16 clause: 3 x 256*512
  unsigned short* pkCmd = pkChi + 256 * 512;
  unsigned short* pkClo = pkCmd + 256 * 512;
  unsigned short* pkLhi = pkClo + 256 * 512;                // bf16 literal: 3 x 384*512
  unsigned short* pkLmd = pkLhi + 384 * 512;
  unsigned short* pkLlo = pkLmd + 384 * 512;
  unsigned short* qkChi = pkLlo + 384 * 512;                // fp16 clause: 2 x 256*512
  unsigned short* qkClo = qkChi + 256 * 512;
  unsigned short* qkLhi = qkClo + 256 * 512;                // fp16 literal: 2 x 384*512
  unsigned short* qkLlo = qkLhi + 384 * 512;
  int* csr  = (int*)(qkLlo + 384 * 512);     // NL*ROWW
  int* csc  = csr + NL * ROWW;               // NC*COLW
  int* rcnt = csc + NC * COLW;               // NL
  int* ccnt = rcnt + NL;                     // NC (contiguous with rcnt)
  float* Lbuf = (float*)d_out;               // literal state lives in d_out

  hipMemsetAsync(rcnt, 0, (NL + NC) * sizeof(int), stream);

  prep_graph<<<4096, 256, 0, stream>>>((float4*)Lbuf, (const float4*)L0,
                                       (float4*)hL, (const float4*)hL0,
                                       (float4*)hC, (const float4*)hC0,
                                       (const float4*)M, csr, csc, rcnt, ccnt);

  build_all<<<1284, 256, 0, stream>>>(WihC, Wlc, WhhC, blc, bihC, bhhC,
                                      WihL, Wcl, WhhL, bcl, bihL, bhhL,
                                      pkChi, pkCmd, pkClo, qkChi, qkClo,
                                      pkLhi, pkLmd, pkLlo, qkLhi, qkLlo,
                                      bsumC, bvecC, bsumL, bvecL);

  // step 0: hidden states are zeros -> truncated K (exactly equivalent)
  clause_bf3<16, false><<<NC / 32, 512, 0, stream>>>(Lbuf, csc, ccnt, pkChi, pkCmd, pkClo,
                                                     bsumC, bvecC, hC, Cs);
  literal_bf3<32, false><<<NL / 16, 512, 0, stream>>>(Cs, csr, rcnt, pkLhi, pkLmd, pkLlo,
                                                      bsumL, bvecL, hL, Lbuf);
  // remaining bf16 steps
  for (int t = 1; t < NBF; ++t) {
    clause_bf3<32, true><<<NC / 32, 512, 0, stream>>>(Lbuf, csc, ccnt, pkChi, pkCmd, pkClo,
                                                      bsumC, bvecC, hC, Cs);
    literal_bf3<48, true><<<NL / 16, 512, 0, stream>>>(Cs, csr, rcnt, pkLhi, pkLmd, pkLlo,
                                                       bsumL, bvecL, hL, Lbuf);
  }
  // fp16 steps
  for (int t = NBF; t < TSTEPS; ++t) {
    clause_f2<<<NC / 32, 512, 0, stream>>>(Lbuf, csc, ccnt, qkChi, qkClo,
                                           bsumC, bvecC, hC, Cs);
    literal_f2<<<NL / 32, 512, 0, stream>>>(Cs, csr, rcnt, qkLhi, qkLlo,
                                            bsumL, bvecL, hL, Lbuf);
  }
}